// Round 5
// baseline (2151.605 us; speedup 1.0000x reference)
//
#include <hip/hip_runtime.h>
#include <cstdint>
#include <math.h>

// Problem sizes (fixed by the reference).
#define NN 50000
#define EE 800000
#define RR 850000   // NN + EE rows

typedef short  bf16x8 __attribute__((ext_vector_type(8)));
typedef float  f32x4  __attribute__((ext_vector_type(4)));

__device__ __forceinline__ float bf2f(unsigned short b) {
    unsigned int u = ((unsigned int)b) << 16;
    return __builtin_bit_cast(float, u);
}
__device__ __forceinline__ unsigned short f2bf(float f) {
    unsigned int u = __builtin_bit_cast(unsigned int, f);
    u = u + 0x7fffu + ((u >> 16) & 1u);
    return (unsigned short)(u >> 16);
}
__device__ __forceinline__ void atomAddF(float* p, float v) {
    unsafeAtomicAdd(p, v);   // global_atomic_add_f32
}
__device__ __forceinline__ void atomAddD(double* p, double v) {
    unsafeAtomicAdd(p, v);   // global_atomic_add_f64
}
// split 8 consecutive f32 into hi/lo bf16 fragments: hi+lo == v to ~2^-16 rel
__device__ __forceinline__ void split8(const float* p, bf16x8& hi, bf16x8& lo) {
    f32x4 v0 = *reinterpret_cast<const f32x4*>(p);
    f32x4 v1 = *reinterpret_cast<const f32x4*>(p + 4);
#pragma unroll
    for (int j = 0; j < 4; j++) {
        unsigned short h0 = f2bf(v0[j]);
        hi[j] = (short)h0; lo[j] = (short)f2bf(v0[j] - bf2f(h0));
        unsigned short h1 = f2bf(v1[j]);
        hi[4 + j] = (short)h1; lo[4 + j] = (short)f2bf(v1[j] - bf2f(h1));
    }
}
__device__ __forceinline__ void split8r(const float* v, bf16x8& hi, bf16x8& lo) {
#pragma unroll
    for (int j = 0; j < 8; j++) {
        unsigned short h = f2bf(v[j]);
        hi[j] = (short)h; lo[j] = (short)f2bf(v[j] - bf2f(h));
    }
}

// dsum[i] = x[i] (self rows); edges atomically added on top afterwards.
__global__ void k_copy_x(const float* __restrict__ x, float* __restrict__ dsum) {
    int i = blockIdx.x * 256 + threadIdx.x;   // covers NN*64 exactly
    dsum[i] = x[i];
}

// dsum[dst] += x[src] for every edge.
__global__ void k_edge_dsum(const float* __restrict__ x, const int* __restrict__ ei,
                            float* __restrict__ dsum) {
    int i = blockIdx.x * 256 + threadIdx.x;   // covers EE*64 exactly
    int e = i >> 6, c = i & 63;
    atomAddF(&dsum[ei[EE + e] * 64 + c], x[ei[e] * 64 + c]);
}

// MFMA row-matmul on f32 data via 3-term hi/lo bf16 split:
//   A*W ~= Al*Wh + Ah*Wl + Ah*Wh   (dropped Al*Wl ~ 2^-16 rel)
// One wave = 16 rows x 64 cols. K=128 (MODE 1..3) or K=64 (MODE 4).
// MODE 1 (unite):    A = [x[rows_src], dsum[rows_dom]]            -> h_pre
// MODE 2 (gconv):    A = [h_norm, msg[rows_dom]] -> h2_pre IN PLACE over h
//                    (wave reads rows [t*16,t*16+16) then writes same rows; race-free)
// MODE 3 (transfer): A = [h2_norm[:N], agg]                       -> t_pre
// MODE 4 (lin):      A = relu(bn(t_pre; stats2, g2, be2)), K=64   -> out_pre (relu'd)
// Per-channel sum/sumsq accumulated in f64 (degenerate-variance channels: var ~ 1e-5
// under mean^2 ~ 1 -> f32 one-pass cancellation is fatal; rstd ~ 300 amplifies).
// inA/outp NOT __restrict__ (alias in MODE 2).
template <int MODE>
__global__ void k_mm(const float* inA, const float* __restrict__ inB,
                     const int* __restrict__ ei, const float* __restrict__ W,
                     const float* __restrict__ bias, const float* __restrict__ bn_fin,
                     const float* __restrict__ g_in, const float* __restrict__ be_in,
                     float* outp, double* __restrict__ stats_raw, int nrows) {
    constexpr int KK = (MODE == 4) ? 2 : 4;
    const int lane = threadIdx.x & 63;
    const int m = lane & 15, quad = lane >> 4;
    const int gwave = (blockIdx.x * blockDim.x + threadIdx.x) >> 6;
    const int nwaves = (gridDim.x * blockDim.x) >> 6;
    const int ntiles = nrows >> 4;   // nrows % 16 == 0 for all modes

    // B fragments (hi/lo): wfh/wfl[kk][ct][j] from W[kk*32 + quad*8 + j][ct*16 + m]
    bf16x8 wfh[KK][4], wfl[KK][4];
#pragma unroll
    for (int kk = 0; kk < KK; kk++)
#pragma unroll
        for (int ct = 0; ct < 4; ct++) {
            float wv[8];
#pragma unroll
            for (int j = 0; j < 8; j++)
                wv[j] = W[(kk * 32 + quad * 8 + j) * 64 + ct * 16 + m];
            split8r(wv, wfh[kk][ct], wfl[kk][ct]);
        }

    float bv[4];
#pragma unroll
    for (int ct = 0; ct < 4; ct++) bv[ct] = bias[ct * 16 + m];

    // MODE 4: fold bn(tpre; g2,be2) into the load: t = relu(v*sc + sh)
    float sc[2][8], sh[2][8];
    if (MODE == 4) {
#pragma unroll
        for (int kk = 0; kk < 2; kk++)
#pragma unroll
            for (int j = 0; j < 8; j++) {
                int c = kk * 32 + quad * 8 + j;
                float mean = bn_fin[c], rstd = bn_fin[64 + c];
                float gg = g_in[c], bb = be_in[c];
                sc[kk][j] = rstd * gg;
                sh[kk][j] = bb - mean * rstd * gg;
            }
    }

    double ssum[4] = {0.0, 0.0, 0.0, 0.0}, ssq[4] = {0.0, 0.0, 0.0, 0.0};

    for (int tile = gwave; tile < ntiles; tile += nwaves) {
        const int r = (tile << 4) + m;   // row this lane loads A-slices for
        bf16x8 ah[KK], al[KK];
        if (MODE == 1) {
            int ar = (r < NN) ? r : ei[r - NN];        // rows_src
            int dm = (r < NN) ? r : ei[EE + r - NN];   // rows_dom
            split8(inA + (size_t)ar * 64 + quad * 8,      ah[0], al[0]);
            split8(inA + (size_t)ar * 64 + 32 + quad * 8, ah[1], al[1]);
            split8(inB + (size_t)dm * 64 + quad * 8,      ah[2], al[2]);
            split8(inB + (size_t)dm * 64 + 32 + quad * 8, ah[3], al[3]);
        } else if (MODE == 2) {
            int dm = (r < NN) ? r : ei[EE + r - NN];
            split8(inA + (size_t)r * 64 + quad * 8,       ah[0], al[0]);
            split8(inA + (size_t)r * 64 + 32 + quad * 8,  ah[1], al[1]);
            split8(inB + (size_t)dm * 64 + quad * 8,      ah[2], al[2]);
            split8(inB + (size_t)dm * 64 + 32 + quad * 8, ah[3], al[3]);
        } else if (MODE == 3) {
            split8(inA + (size_t)r * 64 + quad * 8,       ah[0], al[0]);
            split8(inA + (size_t)r * 64 + 32 + quad * 8,  ah[1], al[1]);
            split8(inB + (size_t)r * 64 + quad * 8,       ah[2], al[2]);
            split8(inB + (size_t)r * 64 + 32 + quad * 8,  ah[3], al[3]);
        } else {
#pragma unroll
            for (int kk = 0; kk < 2; kk++) {
                f32x4 v0 = *reinterpret_cast<const f32x4*>(inB + (size_t)r * 64 + kk * 32 + quad * 8);
                f32x4 v1 = *reinterpret_cast<const f32x4*>(inB + (size_t)r * 64 + kk * 32 + quad * 8 + 4);
                float tv[8];
#pragma unroll
                for (int j = 0; j < 4; j++) {
                    tv[j]     = fmaxf(v0[j] * sc[kk][j]     + sh[kk][j],     0.f);
                    tv[4 + j] = fmaxf(v1[j] * sc[kk][4 + j] + sh[kk][4 + j], 0.f);
                }
                split8r(tv, ah[kk], al[kk]);
            }
        }

        f32x4 zero = {0.f, 0.f, 0.f, 0.f};
        f32x4 acc[4];
#pragma unroll
        for (int ct = 0; ct < 4; ct++) {
            acc[ct] = zero;
#pragma unroll
            for (int kk = 0; kk < KK; kk++)   // small terms first
                acc[ct] = __builtin_amdgcn_mfma_f32_16x16x32_bf16(al[kk], wfh[kk][ct], acc[ct], 0, 0, 0);
#pragma unroll
            for (int kk = 0; kk < KK; kk++)
                acc[ct] = __builtin_amdgcn_mfma_f32_16x16x32_bf16(ah[kk], wfl[kk][ct], acc[ct], 0, 0, 0);
#pragma unroll
            for (int kk = 0; kk < KK; kk++)
                acc[ct] = __builtin_amdgcn_mfma_f32_16x16x32_bf16(ah[kk], wfh[kk][ct], acc[ct], 0, 0, 0);
        }

        // C/D layout: col = ct*16 + (lane&15), row = quad*4 + i  [m89-verified]
#pragma unroll
        for (int ct = 0; ct < 4; ct++)
#pragma unroll
            for (int i = 0; i < 4; i++) {
                size_t row = (size_t)(tile << 4) + quad * 4 + i;
                int col = ct * 16 + m;
                float val = acc[ct][i] + bv[ct];
                if (MODE == 4) val = fmaxf(val, 0.f);   // stats taken AFTER relu (matches ref)
                outp[row * 64 + col] = val;
                ssum[ct] += (double)val;
                ssq[ct]  += (double)val * (double)val;
            }
    }

    // per-channel stats: reduce across the 4 row-quads, one f64 atomic per channel per wave
#pragma unroll
    for (int ct = 0; ct < 4; ct++) {
        double v = ssum[ct], q = ssq[ct];
        v += __shfl_xor(v, 16, 64); v += __shfl_xor(v, 32, 64);
        q += __shfl_xor(q, 16, 64); q += __shfl_xor(q, 32, 64);
        if (quad == 0) {
            atomAddD(&stats_raw[ct * 16 + m], v);
            atomAddD(&stats_raw[64 + ct * 16 + m], q);
        }
    }
}

// mean/var/rstd entirely in double: one-pass E[x^2]-m^2 is safe at f64 precision.
__global__ void k_fin(const double* __restrict__ raw, float* __restrict__ fin, double inv_cnt) {
    int c = threadIdx.x;
    double mean = raw[c] * inv_cnt;
    double var = raw[64 + c] * inv_cnt - mean * mean;
    if (var < 0.0) var = 0.0;
    fin[c] = (float)mean;
    fin[64 + c] = (float)(1.0 / sqrt(var + 1e-5));
}

// Normalize+relu in place (f32) and atomically accumulate into segment buffer.
// WHICH==1: accumulate by rows_dom (-> s). WHICH==2: accumulate by rows_src (-> agg).
template <int WHICH>
__global__ void k_norm(float* __restrict__ h, const int* __restrict__ ei,
                       const float* __restrict__ fin, const float* __restrict__ g,
                       const float* __restrict__ be, float* __restrict__ accbuf) {
    size_t i = (size_t)blockIdx.x * 256 + threadIdx.x;   // covers RR*64 exactly
    int r = (int)(i >> 6), c = (int)(i & 63);
    float hn = fmaxf((h[i] - fin[c]) * fin[64 + c] * g[c] + be[c], 0.f);
    h[i] = hn;
    int t = (WHICH == 1) ? ((r < NN) ? r : ei[EE + r - NN])
                         : ((r < NN) ? r : ei[r - NN]);
    atomAddF(&accbuf[(size_t)t * 64 + c], hn);
}

// msg[dst] += s[src]
__global__ void k_msg(const int* __restrict__ ei, const float* __restrict__ s,
                      float* __restrict__ msg) {
    int i = blockIdx.x * 256 + threadIdx.x;   // covers EE*64 exactly
    int e = i >> 6, c = i & 63;
    atomAddF(&msg[ei[EE + e] * 64 + c], s[ei[e] * 64 + c]);
}

// out = relu(bn(out_pre; stats3, g3, be3)) -> f32
__global__ void k_out(const float* __restrict__ op, const float* __restrict__ fin,
                      const float* __restrict__ g, const float* __restrict__ be,
                      float* __restrict__ out) {
    int i = blockIdx.x * 256 + threadIdx.x;   // covers NN*64 exactly
    int c = i & 63;
    out[i] = fmaxf((op[i] - fin[c]) * fin[64 + c] * g[c] + be[c], 0.f);
}

extern "C" void kernel_launch(void* const* d_in, const int* in_sizes, int n_in,
                              void* d_out, int out_size, void* d_ws, size_t ws_size,
                              hipStream_t stream) {
    const float* x    = (const float*)d_in[0];
    const int*   ei   = (const int*)d_in[1];
    const float* W_un = (const float*)d_in[2];
    const float* b_un = (const float*)d_in[3];
    const float* g1   = (const float*)d_in[4];
    const float* be1  = (const float*)d_in[5];
    const float* W_gc = (const float*)d_in[6];
    const float* b_gc = (const float*)d_in[7];
    const float* g2   = (const float*)d_in[8];
    const float* be2  = (const float*)d_in[9];
    const float* W_tr = (const float*)d_in[10];
    const float* b_tr = (const float*)d_in[11];
    const float* W_li = (const float*)d_in[12];
    const float* b_li = (const float*)d_in[13];
    const float* g3   = (const float*)d_in[14];
    const float* be3  = (const float*)d_in[15];

    float* ws = (float*)d_ws;
    const size_t FN = (size_t)NN * 64;           // 3.2M floats
    const size_t FR = (size_t)RR * 64;           // 54.4M floats
    // Layout (~256.01 MB <= 256 MiB ws):
    float*  hbuf      = ws;                      // [R,64] f32: h, then h2 in place (217.6 MB)
    float*  A0        = ws + FR;                 // dsum -> (re-zero) agg     (12.8 MB)
    float*  A1        = A0 + FN;                 // sbuf -> tpre              (12.8 MB)
    float*  A2        = A1 + FN;                 // msg  -> outpre            (12.8 MB)
    double* stats_raw = (double*)(A2 + FN);      // 4 stages x (sum64 + sumsq64), f64
    float*  stats_fin = (float*)(stats_raw + 512); // 4 stages x (mean64 + rstd64), f32

    // zero dsum/sbuf/msg (f32) + raw stats (f64) in one shot
    hipMemsetAsync(A0, 0, 3 * FN * sizeof(float) + 512 * sizeof(double), stream);

    k_copy_x   <<<12500,  256, 0, stream>>>(x, A0);
    k_edge_dsum<<<200000, 256, 0, stream>>>(x, ei, A0);

    k_mm<1><<<2048, 256, 0, stream>>>(x, A0, ei, W_un, b_un, nullptr, nullptr, nullptr,
                                      hbuf, stats_raw + 0, RR);
    k_fin<<<1, 64, 0, stream>>>(stats_raw + 0, stats_fin + 0, 1.0 / (double)RR);
    k_norm<1><<<212500, 256, 0, stream>>>(hbuf, ei, stats_fin + 0, g1, be1, A1);   // s -> A1
    k_msg<<<200000, 256, 0, stream>>>(ei, A1, A2);                                 // msg -> A2

    k_mm<2><<<2048, 256, 0, stream>>>(hbuf, A2, ei, W_gc, b_gc, nullptr, nullptr, nullptr,
                                      hbuf, stats_raw + 128, RR);                  // h2 in place
    k_fin<<<1, 64, 0, stream>>>(stats_raw + 128, stats_fin + 128, 1.0 / (double)RR);

    hipMemsetAsync(A0, 0, FN * sizeof(float), stream);                             // agg = A0
    k_norm<2><<<212500, 256, 0, stream>>>(hbuf, ei, stats_fin + 128, g2, be2, A0);

    k_mm<3><<<512, 256, 0, stream>>>(hbuf, A0, ei, W_tr, b_tr, nullptr, nullptr, nullptr,
                                     A1, stats_raw + 256, NN);                     // tpre = A1
    k_fin<<<1, 64, 0, stream>>>(stats_raw + 256, stats_fin + 256, 1.0 / (double)NN);

    k_mm<4><<<512, 256, 0, stream>>>(nullptr, A1, ei, W_li, b_li, stats_fin + 256, g2, be2,
                                     A2, stats_raw + 384, NN);                     // outpre = A2
    k_fin<<<1, 64, 0, stream>>>(stats_raw + 384, stats_fin + 384, 1.0 / (double)NN);

    k_out<<<12500, 256, 0, stream>>>(A2, stats_fin + 384, g3, be3, (float*)d_out);
}

// Round 6
// 1896.549 us; speedup vs baseline: 1.1345x; 1.1345x over previous
//
#include <hip/hip_runtime.h>
#include <cstdint>
#include <math.h>

// Problem sizes (fixed by the reference).
#define NN 50000
#define EE 800000
#define RR 850000      // NN + EE rows
#define NT_N 3125      // NN/16
#define NT_R 53125     // RR/16

typedef short  bf16x8 __attribute__((ext_vector_type(8)));
typedef float  f32x4  __attribute__((ext_vector_type(4)));

__device__ __forceinline__ float bf2f(unsigned short b) {
    unsigned int u = ((unsigned int)b) << 16;
    return __builtin_bit_cast(float, u);
}
__device__ __forceinline__ unsigned short f2bf(float f) {
    unsigned int u = __builtin_bit_cast(unsigned int, f);
    u = u + 0x7fffu + ((u >> 16) & 1u);
    return (unsigned short)(u >> 16);
}
__device__ __forceinline__ void atomAddF(float* p, float v) { unsafeAtomicAdd(p, v); }
__device__ __forceinline__ void atomAddD(double* p, double v) { unsafeAtomicAdd(p, v); }

// split 8 consecutive f32 into hi/lo bf16 fragments: hi+lo == v to ~2^-16 rel
__device__ __forceinline__ void split8(const float* p, bf16x8& hi, bf16x8& lo) {
    f32x4 v0 = *reinterpret_cast<const f32x4*>(p);
    f32x4 v1 = *reinterpret_cast<const f32x4*>(p + 4);
#pragma unroll
    for (int j = 0; j < 4; j++) {
        unsigned short h0 = f2bf(v0[j]);
        hi[j] = (short)h0; lo[j] = (short)f2bf(v0[j] - bf2f(h0));
        unsigned short h1 = f2bf(v1[j]);
        hi[4 + j] = (short)h1; lo[4 + j] = (short)f2bf(v1[j] - bf2f(h1));
    }
}
__device__ __forceinline__ void split8r(const float* v, bf16x8& hi, bf16x8& lo) {
#pragma unroll
    for (int j = 0; j < 8; j++) {
        unsigned short h = f2bf(v[j]);
        hi[j] = (short)h; lo[j] = (short)f2bf(v[j] - bf2f(h));
    }
}

// ---------- stage 0: dsum = segment_sum(x, dst) + self ----------
__global__ void k_copy_x(const float* __restrict__ x, float* __restrict__ dsum) {
    int i = blockIdx.x * 256 + threadIdx.x;   // covers NN*64 exactly
    dsum[i] = x[i];
}
__global__ void k_edge_dsum(const float* __restrict__ x, const int* __restrict__ ei,
                            float* __restrict__ dsum) {
    int i = blockIdx.x * 256 + threadIdx.x;   // covers EE*64 exactly
    int e = i >> 6, c = i & 63;
    atomAddF(&dsum[ei[EE + e] * 64 + c], x[ei[e] * 64 + c]);
}

// ---------- u = x @ W_un[0:64], v = dsum @ W_un[64:128]  (no bias) ----------
__global__ void k_uv(const float* __restrict__ x, const float* __restrict__ dsum,
                     const float* __restrict__ W, float* __restrict__ u, float* __restrict__ v) {
    const int lane = threadIdx.x & 63;
    const int m = lane & 15, quad = lane >> 4;
    const int gwave = (blockIdx.x * blockDim.x + threadIdx.x) >> 6;
    const int nwaves = (gridDim.x * blockDim.x) >> 6;

    bf16x8 wfh[4][4], wfl[4][4];
#pragma unroll
    for (int kk = 0; kk < 4; kk++)
#pragma unroll
        for (int ct = 0; ct < 4; ct++) {
            float wv[8];
#pragma unroll
            for (int j = 0; j < 8; j++)
                wv[j] = W[(kk * 32 + quad * 8 + j) * 64 + ct * 16 + m];
            split8r(wv, wfh[kk][ct], wfl[kk][ct]);
        }

    for (int tile = gwave; tile < NT_N; tile += nwaves) {
        const int r = (tile << 4) + m;
        bf16x8 ah[4], al[4];
        split8(x    + (size_t)r * 64 + quad * 8,      ah[0], al[0]);
        split8(x    + (size_t)r * 64 + 32 + quad * 8, ah[1], al[1]);
        split8(dsum + (size_t)r * 64 + quad * 8,      ah[2], al[2]);
        split8(dsum + (size_t)r * 64 + 32 + quad * 8, ah[3], al[3]);

        f32x4 zero = {0.f, 0.f, 0.f, 0.f};
#pragma unroll
        for (int ct = 0; ct < 4; ct++) {
            f32x4 aU = zero, aV = zero;
#pragma unroll
            for (int kk = 0; kk < 2; kk++) {
                aU = __builtin_amdgcn_mfma_f32_16x16x32_bf16(al[kk], wfh[kk][ct], aU, 0, 0, 0);
                aU = __builtin_amdgcn_mfma_f32_16x16x32_bf16(ah[kk], wfl[kk][ct], aU, 0, 0, 0);
                aU = __builtin_amdgcn_mfma_f32_16x16x32_bf16(ah[kk], wfh[kk][ct], aU, 0, 0, 0);
                aV = __builtin_amdgcn_mfma_f32_16x16x32_bf16(al[kk+2], wfh[kk+2][ct], aV, 0, 0, 0);
                aV = __builtin_amdgcn_mfma_f32_16x16x32_bf16(ah[kk+2], wfl[kk+2][ct], aV, 0, 0, 0);
                aV = __builtin_amdgcn_mfma_f32_16x16x32_bf16(ah[kk+2], wfh[kk+2][ct], aV, 0, 0, 0);
            }
#pragma unroll
            for (int i = 0; i < 4; i++) {
                size_t row = (size_t)(tile << 4) + quad * 4 + i;
                u[row * 64 + ct * 16 + m] = aU[i];
                v[row * 64 + ct * 16 + m] = aV[i];
            }
        }
    }
}

// ---------- stage-1 stats over p = u[src]+v[dom]+b_un (no store) ----------
__global__ void k_stats1(const float* __restrict__ u, const float* __restrict__ v,
                         const float* __restrict__ b_un, const int* __restrict__ ei,
                         double* __restrict__ stats_raw) {
    __shared__ double lsum[4][64], lsq[4][64];
    int tid = threadIdx.x, c = tid & 63, w = tid >> 6;
    double s = 0.0, q = 0.0;
    float bc = b_un[c];
    size_t stride = (size_t)gridDim.x * 256;
    for (size_t i = (size_t)blockIdx.x * 256 + tid; i < (size_t)RR * 64; i += stride) {
        int r = (int)(i >> 6);
        int sr = (r < NN) ? r : ei[r - NN];
        int dm = (r < NN) ? r : ei[EE + r - NN];
        float p = u[(size_t)sr * 64 + c] + v[(size_t)dm * 64 + c] + bc;
        s += (double)p; q += (double)p * (double)p;
    }
    lsum[w][c] = s; lsq[w][c] = q;
    __syncthreads();
    if (w == 0) {
        s = lsum[0][c] + lsum[1][c] + lsum[2][c] + lsum[3][c];
        q = lsq[0][c] + lsq[1][c] + lsq[2][c] + lsq[3][c];
        atomAddD(&stats_raw[c], s);
        atomAddD(&stats_raw[64 + c], q);
    }
}

__global__ void k_fin(const double* __restrict__ raw, float* __restrict__ fin, double inv_cnt) {
    int c = threadIdx.x;
    double mean = raw[c] * inv_cnt;
    double var = raw[64 + c] * inv_cnt - mean * mean;
    if (var < 0.0) var = 0.0;
    fin[c] = (float)mean;
    fin[64 + c] = (float)(1.0 / sqrt(var + 1e-5));
}

// ---------- stage-1 scatter: s_tab[dom] += relu(bn1(p)) ----------
__global__ void k_s1(const float* __restrict__ u, const float* __restrict__ v,
                     const float* __restrict__ b_un, const int* __restrict__ ei,
                     const float* __restrict__ fin, const float* __restrict__ g1,
                     const float* __restrict__ be1, float* __restrict__ s_tab) {
    size_t i = (size_t)blockIdx.x * 256 + threadIdx.x;   // covers RR*64 exactly
    int r = (int)(i >> 6), c = (int)(i & 63);
    int sr = (r < NN) ? r : ei[r - NN];
    int dm = (r < NN) ? r : ei[EE + r - NN];
    float p = u[(size_t)sr * 64 + c] + v[(size_t)dm * 64 + c] + b_un[c];
    float hn = fmaxf((p - fin[c]) * fin[64 + c] * g1[c] + be1[c], 0.f);
    atomAddF(&s_tab[(size_t)dm * 64 + c], hn);
}

// ---------- msg[dst] += s_tab[src] ----------
__global__ void k_msg(const int* __restrict__ ei, const float* __restrict__ s,
                      float* __restrict__ msg) {
    int i = blockIdx.x * 256 + threadIdx.x;   // covers EE*64 exactly
    int e = i >> 6, c = i & 63;
    atomAddF(&msg[ei[EE + e] * 64 + c], s[ei[e] * 64 + c]);
}

// ---------- stage 2: h2_pre[row] = [relu(bn1(u[sr]+v[dm]+b_un)), msg[dm]] @ W_gc + b_gc
// PHASE 0: f64 stats of h2_pre.   PHASE 1: h2n = relu(bn2(h2_pre));
//          agg[sr] += h2n; self rows also store h2self. Nothing materialized otherwise.
template <int PHASE>
__global__ void k_stage2(const float* __restrict__ u, const float* __restrict__ v,
                         const float* __restrict__ msg, const int* __restrict__ ei,
                         const float* __restrict__ W, const float* __restrict__ b_un,
                         const float* __restrict__ b_gc,
                         const float* __restrict__ fin1, const float* __restrict__ g1,
                         const float* __restrict__ be1,
                         const float* __restrict__ fin2, const float* __restrict__ g2,
                         const float* __restrict__ be2,
                         float* __restrict__ h2self, float* __restrict__ agg,
                         double* __restrict__ stats_raw) {
    const int lane = threadIdx.x & 63;
    const int m = lane & 15, quad = lane >> 4;
    const int gwave = (blockIdx.x * blockDim.x + threadIdx.x) >> 6;
    const int nwaves = (gridDim.x * blockDim.x) >> 6;

    bf16x8 wfh[4][4], wfl[4][4];
#pragma unroll
    for (int kk = 0; kk < 4; kk++)
#pragma unroll
        for (int ct = 0; ct < 4; ct++) {
            float wv[8];
#pragma unroll
            for (int j = 0; j < 8; j++)
                wv[j] = W[(kk * 32 + quad * 8 + j) * 64 + ct * 16 + m];
            split8r(wv, wfh[kk][ct], wfl[kk][ct]);
        }

    float bv[4];
#pragma unroll
    for (int ct = 0; ct < 4; ct++) bv[ct] = b_gc[ct * 16 + m];

    // bn1 fold for A channels c = kk*32 + quad*8 + j:  hrow = relu((u+v)*s1 + t1)
    float s1f[2][8], t1f[2][8];
#pragma unroll
    for (int kk = 0; kk < 2; kk++)
#pragma unroll
        for (int j = 0; j < 8; j++) {
            int c = kk * 32 + quad * 8 + j;
            float sc = fin1[64 + c] * g1[c];
            s1f[kk][j] = sc;
            t1f[kk][j] = be1[c] + (b_un[c] - fin1[c]) * sc;
        }

    // bn2 fold for output cols (PHASE 1): h2n = relu(val*s2 + t2)
    float s2f[4], t2f[4];
    if (PHASE == 1) {
#pragma unroll
        for (int ct = 0; ct < 4; ct++) {
            int col = ct * 16 + m;
            float sc = fin2[64 + col] * g2[col];
            s2f[ct] = sc;
            t2f[ct] = be2[col] - fin2[col] * sc;
        }
    }

    double ssum[4] = {0,0,0,0}, ssq[4] = {0,0,0,0};

    for (int tile = gwave; tile < NT_R; tile += nwaves) {
        const int r = (tile << 4) + m;
        const bool selftile = (tile < NT_N);   // NN = NT_N*16 exactly
        int sr = selftile ? r : ei[r - NN];
        int dm = selftile ? r : ei[EE + r - NN];

        bf16x8 ah[4], al[4];
#pragma unroll
        for (int kk = 0; kk < 2; kk++) {
            f32x4 u0 = *reinterpret_cast<const f32x4*>(u + (size_t)sr * 64 + kk * 32 + quad * 8);
            f32x4 u1 = *reinterpret_cast<const f32x4*>(u + (size_t)sr * 64 + kk * 32 + quad * 8 + 4);
            f32x4 v0 = *reinterpret_cast<const f32x4*>(v + (size_t)dm * 64 + kk * 32 + quad * 8);
            f32x4 v1 = *reinterpret_cast<const f32x4*>(v + (size_t)dm * 64 + kk * 32 + quad * 8 + 4);
            float tv[8];
#pragma unroll
            for (int j = 0; j < 4; j++) {
                tv[j]     = fmaxf((u0[j] + v0[j]) * s1f[kk][j]     + t1f[kk][j],     0.f);
                tv[4 + j] = fmaxf((u1[j] + v1[j]) * s1f[kk][4 + j] + t1f[kk][4 + j], 0.f);
            }
            split8r(tv, ah[kk], al[kk]);
            split8(msg + (size_t)dm * 64 + kk * 32 + quad * 8, ah[2 + kk], al[2 + kk]);
        }

        f32x4 zero = {0.f, 0.f, 0.f, 0.f};
        f32x4 acc[4];
#pragma unroll
        for (int ct = 0; ct < 4; ct++) {
            acc[ct] = zero;
#pragma unroll
            for (int kk = 0; kk < 4; kk++)
                acc[ct] = __builtin_amdgcn_mfma_f32_16x16x32_bf16(al[kk], wfh[kk][ct], acc[ct], 0, 0, 0);
#pragma unroll
            for (int kk = 0; kk < 4; kk++)
                acc[ct] = __builtin_amdgcn_mfma_f32_16x16x32_bf16(ah[kk], wfl[kk][ct], acc[ct], 0, 0, 0);
#pragma unroll
            for (int kk = 0; kk < 4; kk++)
                acc[ct] = __builtin_amdgcn_mfma_f32_16x16x32_bf16(ah[kk], wfh[kk][ct], acc[ct], 0, 0, 0);
        }

        if (PHASE == 0) {
#pragma unroll
            for (int ct = 0; ct < 4; ct++)
#pragma unroll
                for (int i = 0; i < 4; i++) {
                    float val = acc[ct][i] + bv[ct];
                    ssum[ct] += (double)val;
                    ssq[ct]  += (double)val * (double)val;
                }
        } else {
#pragma unroll
            for (int i = 0; i < 4; i++) {
                // src-node of row tile*16 + quad*4 + i, held by lane (quad, m'=quad*4+i)
                int srv = __shfl(sr, (lane & 48) + quad * 4 + i, 64);
                size_t row = (size_t)(tile << 4) + quad * 4 + i;
#pragma unroll
                for (int ct = 0; ct < 4; ct++) {
                    float val = acc[ct][i] + bv[ct];
                    float h2n = fmaxf(val * s2f[ct] + t2f[ct], 0.f);
                    atomAddF(&agg[(size_t)srv * 64 + ct * 16 + m], h2n);
                    if (selftile) h2self[row * 64 + ct * 16 + m] = h2n;
                }
            }
        }
    }

    if (PHASE == 0) {
#pragma unroll
        for (int ct = 0; ct < 4; ct++) {
            double sv = ssum[ct], qv = ssq[ct];
            sv += __shfl_xor(sv, 16, 64); sv += __shfl_xor(sv, 32, 64);
            qv += __shfl_xor(qv, 16, 64); qv += __shfl_xor(qv, 32, 64);
            if (quad == 0) {
                atomAddD(&stats_raw[ct * 16 + m], sv);
                atomAddD(&stats_raw[64 + ct * 16 + m], qv);
            }
        }
    }
}

// ---------- stage 3/4 GEMMs (N rows), as verified in round 5 ----------
// MODE 3 (transfer): A = [h2self, agg], K=128 -> t_pre + stats
// MODE 4 (lin):      A = relu(bn(t_pre; stats3, g2, be2)), K=64 -> out_pre (relu'd) + stats
template <int MODE>
__global__ void k_mm(const float* __restrict__ inA, const float* __restrict__ inB,
                     const float* __restrict__ W, const float* __restrict__ bias,
                     const float* __restrict__ bn_fin, const float* __restrict__ g_in,
                     const float* __restrict__ be_in,
                     float* __restrict__ outp, double* __restrict__ stats_raw) {
    constexpr int KK = (MODE == 4) ? 2 : 4;
    const int lane = threadIdx.x & 63;
    const int m = lane & 15, quad = lane >> 4;
    const int gwave = (blockIdx.x * blockDim.x + threadIdx.x) >> 6;
    const int nwaves = (gridDim.x * blockDim.x) >> 6;

    bf16x8 wfh[KK][4], wfl[KK][4];
#pragma unroll
    for (int kk = 0; kk < KK; kk++)
#pragma unroll
        for (int ct = 0; ct < 4; ct++) {
            float wv[8];
#pragma unroll
            for (int j = 0; j < 8; j++)
                wv[j] = W[(kk * 32 + quad * 8 + j) * 64 + ct * 16 + m];
            split8r(wv, wfh[kk][ct], wfl[kk][ct]);
        }

    float bv[4];
#pragma unroll
    for (int ct = 0; ct < 4; ct++) bv[ct] = bias[ct * 16 + m];

    float sc[2][8], sh[2][8];
    if (MODE == 4) {
#pragma unroll
        for (int kk = 0; kk < 2; kk++)
#pragma unroll
            for (int j = 0; j < 8; j++) {
                int c = kk * 32 + quad * 8 + j;
                float mean = bn_fin[c], rstd = bn_fin[64 + c];
                sc[kk][j] = rstd * g_in[c];
                sh[kk][j] = be_in[c] - mean * rstd * g_in[c];
            }
    }

    double ssum[4] = {0,0,0,0}, ssq[4] = {0,0,0,0};

    for (int tile = gwave; tile < NT_N; tile += nwaves) {
        const int r = (tile << 4) + m;
        bf16x8 ah[KK], al[KK];
        if (MODE == 3) {
            split8(inA + (size_t)r * 64 + quad * 8,      ah[0], al[0]);
            split8(inA + (size_t)r * 64 + 32 + quad * 8, ah[1], al[1]);
            split8(inB + (size_t)r * 64 + quad * 8,      ah[2], al[2]);
            split8(inB + (size_t)r * 64 + 32 + quad * 8, ah[3], al[3]);
        } else {
#pragma unroll
            for (int kk = 0; kk < 2; kk++) {
                f32x4 v0 = *reinterpret_cast<const f32x4*>(inB + (size_t)r * 64 + kk * 32 + quad * 8);
                f32x4 v1 = *reinterpret_cast<const f32x4*>(inB + (size_t)r * 64 + kk * 32 + quad * 8 + 4);
                float tv[8];
#pragma unroll
                for (int j = 0; j < 4; j++) {
                    tv[j]     = fmaxf(v0[j] * sc[kk][j]     + sh[kk][j],     0.f);
                    tv[4 + j] = fmaxf(v1[j] * sc[kk][4 + j] + sh[kk][4 + j], 0.f);
                }
                split8r(tv, ah[kk], al[kk]);
            }
        }

        f32x4 zero = {0.f, 0.f, 0.f, 0.f};
        f32x4 acc[4];
#pragma unroll
        for (int ct = 0; ct < 4; ct++) {
            acc[ct] = zero;
#pragma unroll
            for (int kk = 0; kk < KK; kk++)
                acc[ct] = __builtin_amdgcn_mfma_f32_16x16x32_bf16(al[kk], wfh[kk][ct], acc[ct], 0, 0, 0);
#pragma unroll
            for (int kk = 0; kk < KK; kk++)
                acc[ct] = __builtin_amdgcn_mfma_f32_16x16x32_bf16(ah[kk], wfl[kk][ct], acc[ct], 0, 0, 0);
#pragma unroll
            for (int kk = 0; kk < KK; kk++)
                acc[ct] = __builtin_amdgcn_mfma_f32_16x16x32_bf16(ah[kk], wfh[kk][ct], acc[ct], 0, 0, 0);
        }

#pragma unroll
        for (int ct = 0; ct < 4; ct++)
#pragma unroll
            for (int i = 0; i < 4; i++) {
                size_t row = (size_t)(tile << 4) + quad * 4 + i;
                float val = acc[ct][i] + bv[ct];
                if (MODE == 4) val = fmaxf(val, 0.f);
                outp[row * 64 + ct * 16 + m] = val;
                ssum[ct] += (double)val;
                ssq[ct]  += (double)val * (double)val;
            }
    }

#pragma unroll
    for (int ct = 0; ct < 4; ct++) {
        double sv = ssum[ct], qv = ssq[ct];
        sv += __shfl_xor(sv, 16, 64); sv += __shfl_xor(sv, 32, 64);
        qv += __shfl_xor(qv, 16, 64); qv += __shfl_xor(qv, 32, 64);
        if (quad == 0) {
            atomAddD(&stats_raw[ct * 16 + m], sv);
            atomAddD(&stats_raw[64 + ct * 16 + m], qv);
        }
    }
}

// out = relu(bn(out_pre; stats4, g3, be3)) -> f32
__global__ void k_out(const float* __restrict__ op, const float* __restrict__ fin,
                      const float* __restrict__ g, const float* __restrict__ be,
                      float* __restrict__ out) {
    int i = blockIdx.x * 256 + threadIdx.x;   // covers NN*64 exactly
    int c = i & 63;
    out[i] = fmaxf((op[i] - fin[c]) * fin[64 + c] * g[c] + be[c], 0.f);
}

extern "C" void kernel_launch(void* const* d_in, const int* in_sizes, int n_in,
                              void* d_out, int out_size, void* d_ws, size_t ws_size,
                              hipStream_t stream) {
    const float* x    = (const float*)d_in[0];
    const int*   ei   = (const int*)d_in[1];
    const float* W_un = (const float*)d_in[2];
    const float* b_un = (const float*)d_in[3];
    const float* g1   = (const float*)d_in[4];
    const float* be1  = (const float*)d_in[5];
    const float* W_gc = (const float*)d_in[6];
    const float* b_gc = (const float*)d_in[7];
    const float* g2   = (const float*)d_in[8];
    const float* be2  = (const float*)d_in[9];
    const float* W_tr = (const float*)d_in[10];
    const float* b_tr = (const float*)d_in[11];
    const float* W_li = (const float*)d_in[12];
    const float* b_li = (const float*)d_in[13];
    const float* g3   = (const float*)d_in[14];
    const float* be3  = (const float*)d_in[15];

    float* ws = (float*)d_ws;
    const size_t FN = (size_t)NN * 64;           // 3.2M floats (12.8 MB)
    // zero-init group first (one memset): s_tab | msg | agg | stats_raw(f64 x512)
    float*  s_tab     = ws;
    float*  msg       = ws + FN;
    float*  agg       = ws + 2 * FN;
    double* stats_raw = (double*)(ws + 3 * FN);
    // non-zeroed tables:
    float*  dsum      = (float*)(stats_raw + 512);
    float*  u         = dsum + FN;
    float*  v         = u + FN;
    float*  h2self    = v + FN;
    float*  tpre      = h2self + FN;
    float*  outpre    = tpre + FN;
    float*  stats_fin = outpre + FN;             // 4 x 128 f32
    // total ~115 MB << 256 MiB

    hipMemsetAsync(ws, 0, 3 * FN * sizeof(float) + 512 * sizeof(double), stream);

    // stage 0: dsum
    k_copy_x   <<<12500,  256, 0, stream>>>(x, dsum);
    k_edge_dsum<<<200000, 256, 0, stream>>>(x, ei, dsum);

    // per-node tables u, v
    k_uv<<<512, 256, 0, stream>>>(x, dsum, W_un, u, v);

    // stage-1 stats + scatter (h never materialized)
    k_stats1<<<1024, 256, 0, stream>>>(u, v, b_un, ei, stats_raw + 0);
    k_fin<<<1, 64, 0, stream>>>(stats_raw + 0, stats_fin + 0, 1.0 / (double)RR);
    k_s1<<<212500, 256, 0, stream>>>(u, v, b_un, ei, stats_fin + 0, g1, be1, s_tab);
    k_msg<<<200000, 256, 0, stream>>>(ei, s_tab, msg);

    // stage-2 stats + scatter (h2 never materialized; self rows -> h2self)
    k_stage2<0><<<2048, 256, 0, stream>>>(u, v, msg, ei, W_gc, b_un, b_gc,
                                          stats_fin + 0, g1, be1, nullptr, g2, be2,
                                          nullptr, nullptr, stats_raw + 128);
    k_fin<<<1, 64, 0, stream>>>(stats_raw + 128, stats_fin + 128, 1.0 / (double)RR);
    k_stage2<1><<<2048, 256, 0, stream>>>(u, v, msg, ei, W_gc, b_un, b_gc,
                                          stats_fin + 0, g1, be1, stats_fin + 128, g2, be2,
                                          h2self, agg, nullptr);

    // stage 3: t_pre = [h2self, agg] @ W_tr + b_tr, stats3
    k_mm<3><<<512, 256, 0, stream>>>(h2self, agg, W_tr, b_tr, nullptr, nullptr, nullptr,
                                     tpre, stats_raw + 256);
    k_fin<<<1, 64, 0, stream>>>(stats_raw + 256, stats_fin + 256, 1.0 / (double)NN);

    // stage 4: out_pre = relu(bn(tpre; stats3, g2, be2) @ W_li + b_li), stats4
    k_mm<4><<<512, 256, 0, stream>>>(nullptr, tpre, W_li, b_li, stats_fin + 256, g2, be2,
                                     outpre, stats_raw + 384);
    k_fin<<<1, 64, 0, stream>>>(stats_raw + 384, stats_fin + 384, 1.0 / (double)NN);

    k_out<<<12500, 256, 0, stream>>>(outpre, stats_fin + 384, g3, be3, (float*)d_out);
}

// Round 7
// 1600.924 us; speedup vs baseline: 1.3440x; 1.1847x over previous
//
#include <hip/hip_runtime.h>
#include <cstdint>
#include <math.h>

// Problem sizes (fixed by the reference).
#define NN 50000
#define EE 800000
#define RR 850000      // NN + EE rows
#define NT_N 3125      // NN/16
#define NT_R 53125     // RR/16

typedef short  bf16x8 __attribute__((ext_vector_type(8)));
typedef float  f32x4  __attribute__((ext_vector_type(4)));

__device__ __forceinline__ float bf2f(unsigned short b) {
    unsigned int u = ((unsigned int)b) << 16;
    return __builtin_bit_cast(float, u);
}
__device__ __forceinline__ unsigned short f2bf(float f) {
    unsigned int u = __builtin_bit_cast(unsigned int, f);
    u = u + 0x7fffu + ((u >> 16) & 1u);
    return (unsigned short)(u >> 16);
}
__device__ __forceinline__ void atomAddF(float* p, float v) { unsafeAtomicAdd(p, v); }
__device__ __forceinline__ void atomAddD(double* p, double v) { unsafeAtomicAdd(p, v); }
__device__ __forceinline__ void atomAddI(int* p, int v) { atomicAdd(p, v); }

// split 8 consecutive f32 into hi/lo bf16 fragments: hi+lo == v to ~2^-16 rel
__device__ __forceinline__ void split8(const float* p, bf16x8& hi, bf16x8& lo) {
    f32x4 v0 = *reinterpret_cast<const f32x4*>(p);
    f32x4 v1 = *reinterpret_cast<const f32x4*>(p + 4);
#pragma unroll
    for (int j = 0; j < 4; j++) {
        unsigned short h0 = f2bf(v0[j]);
        hi[j] = (short)h0; lo[j] = (short)f2bf(v0[j] - bf2f(h0));
        unsigned short h1 = f2bf(v1[j]);
        hi[4 + j] = (short)h1; lo[4 + j] = (short)f2bf(v1[j] - bf2f(h1));
    }
}
__device__ __forceinline__ void split8r(const float* v, bf16x8& hi, bf16x8& lo) {
#pragma unroll
    for (int j = 0; j < 8; j++) {
        unsigned short h = f2bf(v[j]);
        hi[j] = (short)h; lo[j] = (short)f2bf(v[j] - bf2f(h));
    }
}

// ---------- stage 0: dsum = segment_sum(x, dst) + self ----------
__global__ void k_copy_x(const float* __restrict__ x, float* __restrict__ dsum) {
    int i = blockIdx.x * 256 + threadIdx.x;   // covers NN*64 exactly
    dsum[i] = x[i];
}
__global__ void k_edge_dsum(const float* __restrict__ x, const int* __restrict__ ei,
                            float* __restrict__ dsum) {
    int i = blockIdx.x * 256 + threadIdx.x;   // covers EE*64 exactly
    int e = i >> 6, c = i & 63;
    atomAddF(&dsum[ei[EE + e] * 64 + c], x[ei[e] * 64 + c]);
}

// ---------- degree counts (for analytic stage-1 stats) ----------
__global__ void k_deg(const int* __restrict__ ei, int* __restrict__ od, int* __restrict__ id) {
    int e = blockIdx.x * 256 + threadIdx.x;   // covers EE exactly
    atomAddI(&od[ei[e]], 1);
    atomAddI(&id[ei[EE + e]], 1);
}

// ---------- u = x@W_top, v = dsum@W_bot, u2 = dsum@W_top ----------
__global__ void k_uv3(const float* __restrict__ x, const float* __restrict__ dsum,
                      const float* __restrict__ W, float* __restrict__ u,
                      float* __restrict__ v, float* __restrict__ u2) {
    const int lane = threadIdx.x & 63;
    const int m = lane & 15, quad = lane >> 4;
    const int gwave = (blockIdx.x * blockDim.x + threadIdx.x) >> 6;
    const int nwaves = (gridDim.x * blockDim.x) >> 6;

    bf16x8 wfh[4][4], wfl[4][4];
#pragma unroll
    for (int kk = 0; kk < 4; kk++)
#pragma unroll
        for (int ct = 0; ct < 4; ct++) {
            float wv[8];
#pragma unroll
            for (int j = 0; j < 8; j++)
                wv[j] = W[(kk * 32 + quad * 8 + j) * 64 + ct * 16 + m];
            split8r(wv, wfh[kk][ct], wfl[kk][ct]);
        }

    for (int tile = gwave; tile < NT_N; tile += nwaves) {
        const int r = (tile << 4) + m;
        bf16x8 ah[4], al[4];
        split8(x    + (size_t)r * 64 + quad * 8,      ah[0], al[0]);
        split8(x    + (size_t)r * 64 + 32 + quad * 8, ah[1], al[1]);
        split8(dsum + (size_t)r * 64 + quad * 8,      ah[2], al[2]);
        split8(dsum + (size_t)r * 64 + 32 + quad * 8, ah[3], al[3]);

        f32x4 zero = {0.f, 0.f, 0.f, 0.f};
#pragma unroll
        for (int ct = 0; ct < 4; ct++) {
            f32x4 aU = zero, aV = zero, aU2 = zero;
#pragma unroll
            for (int kk = 0; kk < 2; kk++) {
                aU  = __builtin_amdgcn_mfma_f32_16x16x32_bf16(al[kk],   wfh[kk][ct],   aU,  0, 0, 0);
                aU  = __builtin_amdgcn_mfma_f32_16x16x32_bf16(ah[kk],   wfl[kk][ct],   aU,  0, 0, 0);
                aU  = __builtin_amdgcn_mfma_f32_16x16x32_bf16(ah[kk],   wfh[kk][ct],   aU,  0, 0, 0);
                aV  = __builtin_amdgcn_mfma_f32_16x16x32_bf16(al[kk+2], wfh[kk+2][ct], aV,  0, 0, 0);
                aV  = __builtin_amdgcn_mfma_f32_16x16x32_bf16(ah[kk+2], wfl[kk+2][ct], aV,  0, 0, 0);
                aV  = __builtin_amdgcn_mfma_f32_16x16x32_bf16(ah[kk+2], wfh[kk+2][ct], aV,  0, 0, 0);
                aU2 = __builtin_amdgcn_mfma_f32_16x16x32_bf16(al[kk+2], wfh[kk][ct],   aU2, 0, 0, 0);
                aU2 = __builtin_amdgcn_mfma_f32_16x16x32_bf16(ah[kk+2], wfl[kk][ct],   aU2, 0, 0, 0);
                aU2 = __builtin_amdgcn_mfma_f32_16x16x32_bf16(ah[kk+2], wfh[kk][ct],   aU2, 0, 0, 0);
            }
#pragma unroll
            for (int i = 0; i < 4; i++) {
                size_t row = (size_t)(tile << 4) + quad * 4 + i;
                u [row * 64 + ct * 16 + m] = aU[i];
                v [row * 64 + ct * 16 + m] = aV[i];
                u2[row * 64 + ct * 16 + m] = aU2[i];
            }
        }
    }
}

// ---------- analytic stage-1 stats over p = u[src]+v[dom]+b  (w := u+v part) ----------
// Sum_rows w      = Sum_n (1+od)u + (1+id)v
// Sum_rows w^2    = Sum_n (1+od)u^2 + (1+id)v^2 + 2*Sum_n v*u2   [cross term collapses]
__global__ void k_stats1a(const float* __restrict__ u, const float* __restrict__ v,
                          const float* __restrict__ u2, const int* __restrict__ od,
                          const int* __restrict__ id, double* __restrict__ stats_raw) {
    __shared__ double lsum[4][64], lsq[4][64];
    int tid = threadIdx.x, c = tid & 63, w = tid >> 6;
    double a1 = 0.0, a2 = 0.0;
    for (int n = blockIdx.x * 4 + w; n < NN; n += gridDim.x * 4) {
        double uu = u[(size_t)n * 64 + c], vv = v[(size_t)n * 64 + c];
        double uu2 = u2[(size_t)n * 64 + c];
        double wod = 1.0 + od[n], wid = 1.0 + id[n];
        a1 += wod * uu + wid * vv;
        a2 += wod * uu * uu + wid * vv * vv + 2.0 * vv * uu2;
    }
    lsum[w][c] = a1; lsq[w][c] = a2;
    __syncthreads();
    if (w == 0) {
        a1 = lsum[0][c] + lsum[1][c] + lsum[2][c] + lsum[3][c];
        a2 = lsq[0][c] + lsq[1][c] + lsq[2][c] + lsq[3][c];
        atomAddD(&stats_raw[c], a1);
        atomAddD(&stats_raw[64 + c], a2);
    }
}

// stage-1 finalize: mean = A1/R + b (bias shift); var shift-invariant.
__global__ void k_fin1(const double* __restrict__ raw, const float* __restrict__ b,
                       float* __restrict__ fin, double inv_cnt) {
    int c = threadIdx.x;
    double m1 = raw[c] * inv_cnt;
    double var = raw[64 + c] * inv_cnt - m1 * m1;
    if (var < 0.0) var = 0.0;
    fin[c] = (float)(m1 + (double)b[c]);
    fin[64 + c] = (float)(1.0 / sqrt(var + 1e-5));
}

__global__ void k_fin(const double* __restrict__ raw, float* __restrict__ fin, double inv_cnt) {
    int c = threadIdx.x;
    double mean = raw[c] * inv_cnt;
    double var = raw[64 + c] * inv_cnt - mean * mean;
    if (var < 0.0) var = 0.0;
    fin[c] = (float)mean;
    fin[64 + c] = (float)(1.0 / sqrt(var + 1e-5));
}

// ---------- stage-1 scatter: s_tab[dom] += relu(bn1(p)) ----------
__global__ void k_s1(const float* __restrict__ u, const float* __restrict__ v,
                     const float* __restrict__ b_un, const int* __restrict__ ei,
                     const float* __restrict__ fin, const float* __restrict__ g1,
                     const float* __restrict__ be1, float* __restrict__ s_tab) {
    size_t i = (size_t)blockIdx.x * 256 + threadIdx.x;   // covers RR*64 exactly
    int r = (int)(i >> 6), c = (int)(i & 63);
    int sr = (r < NN) ? r : ei[r - NN];
    int dm = (r < NN) ? r : ei[EE + r - NN];
    float p = u[(size_t)sr * 64 + c] + v[(size_t)dm * 64 + c] + b_un[c];
    float hn = fmaxf((p - fin[c]) * fin[64 + c] * g1[c] + be1[c], 0.f);
    atomAddF(&s_tab[(size_t)dm * 64 + c], hn);
}

// ---------- msg[dst] += s_tab[src] ----------
__global__ void k_msg(const int* __restrict__ ei, const float* __restrict__ s,
                      float* __restrict__ msg) {
    int i = blockIdx.x * 256 + threadIdx.x;   // covers EE*64 exactly
    int e = i >> 6, c = i & 63;
    atomAddF(&msg[ei[EE + e] * 64 + c], s[ei[e] * 64 + c]);
}

// ---------- stage-2 phase 0: h2_pre[row] = [relu(bn1(u[sr]+v[dm]+b_un)), msg[dm]] @ W_gc + b_gc
// Writes h2_pre (f32, all R rows) AND f64 stats. One gather pass total for stage 2.
__global__ void k_ph0(const float* __restrict__ u, const float* __restrict__ v,
                      const float* __restrict__ msg, const int* __restrict__ ei,
                      const float* __restrict__ W, const float* __restrict__ b_un,
                      const float* __restrict__ b_gc,
                      const float* __restrict__ fin1, const float* __restrict__ g1,
                      const float* __restrict__ be1,
                      float* __restrict__ h2pre, double* __restrict__ stats_raw) {
    const int lane = threadIdx.x & 63;
    const int m = lane & 15, quad = lane >> 4;
    const int gwave = (blockIdx.x * blockDim.x + threadIdx.x) >> 6;
    const int nwaves = (gridDim.x * blockDim.x) >> 6;

    bf16x8 wfh[4][4], wfl[4][4];
#pragma unroll
    for (int kk = 0; kk < 4; kk++)
#pragma unroll
        for (int ct = 0; ct < 4; ct++) {
            float wv[8];
#pragma unroll
            for (int j = 0; j < 8; j++)
                wv[j] = W[(kk * 32 + quad * 8 + j) * 64 + ct * 16 + m];
            split8r(wv, wfh[kk][ct], wfl[kk][ct]);
        }

    float bv[4];
#pragma unroll
    for (int ct = 0; ct < 4; ct++) bv[ct] = b_gc[ct * 16 + m];

    // bn1 fold for A channels c = kk*32 + quad*8 + j:  hrow = relu((u+v)*s1 + t1)
    float s1f[2][8], t1f[2][8];
#pragma unroll
    for (int kk = 0; kk < 2; kk++)
#pragma unroll
        for (int j = 0; j < 8; j++) {
            int c = kk * 32 + quad * 8 + j;
            float sc = fin1[64 + c] * g1[c];
            s1f[kk][j] = sc;
            t1f[kk][j] = be1[c] + (b_un[c] - fin1[c]) * sc;
        }

    double ssum[4] = {0,0,0,0}, ssq[4] = {0,0,0,0};

    for (int tile = gwave; tile < NT_R; tile += nwaves) {
        const int r = (tile << 4) + m;
        const bool selftile = (tile < NT_N);
        int sr = selftile ? r : ei[r - NN];
        int dm = selftile ? r : ei[EE + r - NN];

        bf16x8 ah[4], al[4];
#pragma unroll
        for (int kk = 0; kk < 2; kk++) {
            f32x4 u0 = *reinterpret_cast<const f32x4*>(u + (size_t)sr * 64 + kk * 32 + quad * 8);
            f32x4 u1 = *reinterpret_cast<const f32x4*>(u + (size_t)sr * 64 + kk * 32 + quad * 8 + 4);
            f32x4 v0 = *reinterpret_cast<const f32x4*>(v + (size_t)dm * 64 + kk * 32 + quad * 8);
            f32x4 v1 = *reinterpret_cast<const f32x4*>(v + (size_t)dm * 64 + kk * 32 + quad * 8 + 4);
            float tv[8];
#pragma unroll
            for (int j = 0; j < 4; j++) {
                tv[j]     = fmaxf((u0[j] + v0[j]) * s1f[kk][j]     + t1f[kk][j],     0.f);
                tv[4 + j] = fmaxf((u1[j] + v1[j]) * s1f[kk][4 + j] + t1f[kk][4 + j], 0.f);
            }
            split8r(tv, ah[kk], al[kk]);
            split8(msg + (size_t)dm * 64 + kk * 32 + quad * 8, ah[2 + kk], al[2 + kk]);
        }

        f32x4 zero = {0.f, 0.f, 0.f, 0.f};
        f32x4 acc[4];
#pragma unroll
        for (int ct = 0; ct < 4; ct++) {
            acc[ct] = zero;
#pragma unroll
            for (int kk = 0; kk < 4; kk++)
                acc[ct] = __builtin_amdgcn_mfma_f32_16x16x32_bf16(al[kk], wfh[kk][ct], acc[ct], 0, 0, 0);
#pragma unroll
            for (int kk = 0; kk < 4; kk++)
                acc[ct] = __builtin_amdgcn_mfma_f32_16x16x32_bf16(ah[kk], wfl[kk][ct], acc[ct], 0, 0, 0);
#pragma unroll
            for (int kk = 0; kk < 4; kk++)
                acc[ct] = __builtin_amdgcn_mfma_f32_16x16x32_bf16(ah[kk], wfh[kk][ct], acc[ct], 0, 0, 0);
        }

#pragma unroll
        for (int ct = 0; ct < 4; ct++)
#pragma unroll
            for (int i = 0; i < 4; i++) {
                size_t row = (size_t)(tile << 4) + quad * 4 + i;
                float val = acc[ct][i] + bv[ct];
                h2pre[row * 64 + ct * 16 + m] = val;
                ssum[ct] += (double)val;
                ssq[ct]  += (double)val * (double)val;
            }
    }

#pragma unroll
    for (int ct = 0; ct < 4; ct++) {
        double sv = ssum[ct], qv = ssq[ct];
        sv += __shfl_xor(sv, 16, 64); sv += __shfl_xor(sv, 32, 64);
        qv += __shfl_xor(qv, 16, 64); qv += __shfl_xor(qv, 32, 64);
        if (quad == 0) {
            atomAddD(&stats_raw[ct * 16 + m], sv);
            atomAddD(&stats_raw[64 + ct * 16 + m], qv);
        }
    }
}

// ---------- stage-2 scatter: stream h2_pre, agg[src] += relu(bn2(h2_pre)) ----------
__global__ void k_scatter2(const float* __restrict__ h2pre, const int* __restrict__ ei,
                           const float* __restrict__ fin2, const float* __restrict__ g2,
                           const float* __restrict__ be2, float* __restrict__ agg) {
    size_t i = (size_t)blockIdx.x * 256 + threadIdx.x;   // covers RR*64 exactly
    int r = (int)(i >> 6), c = (int)(i & 63);
    float sc = fin2[64 + c] * g2[c];
    float h2n = fmaxf((h2pre[i] - fin2[c]) * sc + be2[c], 0.f);
    int sr = (r < NN) ? r : ei[r - NN];
    atomAddF(&agg[(size_t)sr * 64 + c], h2n);
}

// ---------- stage 3: t_pre = [relu(bn2(h2pre[:N])), agg] @ W_tr + b_tr, stats3 ----------
__global__ void k_mm3(const float* __restrict__ h2pre, const float* __restrict__ agg,
                      const float* __restrict__ W, const float* __restrict__ bias,
                      const float* __restrict__ fin2, const float* __restrict__ g2,
                      const float* __restrict__ be2,
                      float* __restrict__ outp, double* __restrict__ stats_raw) {
    const int lane = threadIdx.x & 63;
    const int m = lane & 15, quad = lane >> 4;
    const int gwave = (blockIdx.x * blockDim.x + threadIdx.x) >> 6;
    const int nwaves = (gridDim.x * blockDim.x) >> 6;

    bf16x8 wfh[4][4], wfl[4][4];
#pragma unroll
    for (int kk = 0; kk < 4; kk++)
#pragma unroll
        for (int ct = 0; ct < 4; ct++) {
            float wv[8];
#pragma unroll
            for (int j = 0; j < 8; j++)
                wv[j] = W[(kk * 32 + quad * 8 + j) * 64 + ct * 16 + m];
            split8r(wv, wfh[kk][ct], wfl[kk][ct]);
        }

    float bv[4];
#pragma unroll
    for (int ct = 0; ct < 4; ct++) bv[ct] = bias[ct * 16 + m];

    // bn2 fold for A-half channels
    float s2f[2][8], t2f[2][8];
#pragma unroll
    for (int kk = 0; kk < 2; kk++)
#pragma unroll
        for (int j = 0; j < 8; j++) {
            int c = kk * 32 + quad * 8 + j;
            float sc = fin2[64 + c] * g2[c];
            s2f[kk][j] = sc;
            t2f[kk][j] = be2[c] - fin2[c] * sc;
        }

    double ssum[4] = {0,0,0,0}, ssq[4] = {0,0,0,0};

    for (int tile = gwave; tile < NT_N; tile += nwaves) {
        const int r = (tile << 4) + m;
        bf16x8 ah[4], al[4];
#pragma unroll
        for (int kk = 0; kk < 2; kk++) {
            f32x4 v0 = *reinterpret_cast<const f32x4*>(h2pre + (size_t)r * 64 + kk * 32 + quad * 8);
            f32x4 v1 = *reinterpret_cast<const f32x4*>(h2pre + (size_t)r * 64 + kk * 32 + quad * 8 + 4);
            float tv[8];
#pragma unroll
            for (int j = 0; j < 4; j++) {
                tv[j]     = fmaxf(v0[j] * s2f[kk][j]     + t2f[kk][j],     0.f);
                tv[4 + j] = fmaxf(v1[j] * s2f[kk][4 + j] + t2f[kk][4 + j], 0.f);
            }
            split8r(tv, ah[kk], al[kk]);
        }
        split8(agg + (size_t)r * 64 + quad * 8,      ah[2], al[2]);
        split8(agg + (size_t)r * 64 + 32 + quad * 8, ah[3], al[3]);

        f32x4 zero = {0.f, 0.f, 0.f, 0.f};
        f32x4 acc[4];
#pragma unroll
        for (int ct = 0; ct < 4; ct++) {
            acc[ct] = zero;
#pragma unroll
            for (int kk = 0; kk < 4; kk++)
                acc[ct] = __builtin_amdgcn_mfma_f32_16x16x32_bf16(al[kk], wfh[kk][ct], acc[ct], 0, 0, 0);
#pragma unroll
            for (int kk = 0; kk < 4; kk++)
                acc[ct] = __builtin_amdgcn_mfma_f32_16x16x32_bf16(ah[kk], wfl[kk][ct], acc[ct], 0, 0, 0);
#pragma unroll
            for (int kk = 0; kk < 4; kk++)
                acc[ct] = __builtin_amdgcn_mfma_f32_16x16x32_bf16(ah[kk], wfh[kk][ct], acc[ct], 0, 0, 0);
        }

#pragma unroll
        for (int ct = 0; ct < 4; ct++)
#pragma unroll
            for (int i = 0; i < 4; i++) {
                size_t row = (size_t)(tile << 4) + quad * 4 + i;
                float val = acc[ct][i] + bv[ct];
                outp[row * 64 + ct * 16 + m] = val;
                ssum[ct] += (double)val;
                ssq[ct]  += (double)val * (double)val;
            }
    }

#pragma unroll
    for (int ct = 0; ct < 4; ct++) {
        double sv = ssum[ct], qv = ssq[ct];
        sv += __shfl_xor(sv, 16, 64); sv += __shfl_xor(sv, 32, 64);
        qv += __shfl_xor(qv, 16, 64); qv += __shfl_xor(qv, 32, 64);
        if (quad == 0) {
            atomAddD(&stats_raw[ct * 16 + m], sv);
            atomAddD(&stats_raw[64 + ct * 16 + m], qv);
        }
    }
}

// ---------- stage 4: out_pre = relu( relu(bn(tpre;stats3,g2,be2)) @ W_li + b_li ), stats4 ----------
__global__ void k_mm4(const float* __restrict__ tpre, const float* __restrict__ W,
                      const float* __restrict__ bias, const float* __restrict__ fin3,
                      const float* __restrict__ g2, const float* __restrict__ be2,
                      float* __restrict__ outp, double* __restrict__ stats_raw) {
    const int lane = threadIdx.x & 63;
    const int m = lane & 15, quad = lane >> 4;
    const int gwave = (blockIdx.x * blockDim.x + threadIdx.x) >> 6;
    const int nwaves = (gridDim.x * blockDim.x) >> 6;

    bf16x8 wfh[2][4], wfl[2][4];
#pragma unroll
    for (int kk = 0; kk < 2; kk++)
#pragma unroll
        for (int ct = 0; ct < 4; ct++) {
            float wv[8];
#pragma unroll
            for (int j = 0; j < 8; j++)
                wv[j] = W[(kk * 32 + quad * 8 + j) * 64 + ct * 16 + m];
            split8r(wv, wfh[kk][ct], wfl[kk][ct]);
        }

    float bv[4];
#pragma unroll
    for (int ct = 0; ct < 4; ct++) bv[ct] = bias[ct * 16 + m];

    float sc[2][8], sh[2][8];
#pragma unroll
    for (int kk = 0; kk < 2; kk++)
#pragma unroll
        for (int j = 0; j < 8; j++) {
            int c = kk * 32 + quad * 8 + j;
            float s = fin3[64 + c] * g2[c];
            sc[kk][j] = s;
            sh[kk][j] = be2[c] - fin3[c] * s;
        }

    double ssum[4] = {0,0,0,0}, ssq[4] = {0,0,0,0};

    for (int tile = gwave; tile < NT_N; tile += nwaves) {
        const int r = (tile << 4) + m;
        bf16x8 ah[2], al[2];
#pragma unroll
        for (int kk = 0; kk < 2; kk++) {
            f32x4 v0 = *reinterpret_cast<const f32x4*>(tpre + (size_t)r * 64 + kk * 32 + quad * 8);
            f32x4 v1 = *reinterpret_cast<const f32x4*>(tpre + (size_t)r * 64 + kk * 32 + quad * 8 + 4);
            float tv[8];
#pragma unroll
            for (int j = 0; j < 4; j++) {
                tv[j]     = fmaxf(v0[j] * sc[kk][j]     + sh[kk][j],     0.f);
                tv[4 + j] = fmaxf(v1[j] * sc[kk][4 + j] + sh[kk][4 + j], 0.f);
            }
            split8r(tv, ah[kk], al[kk]);
        }

        f32x4 zero = {0.f, 0.f, 0.f, 0.f};
        f32x4 acc[4];
#pragma unroll
        for (int ct = 0; ct < 4; ct++) {
            acc[ct] = zero;
#pragma unroll
            for (int kk = 0; kk < 2; kk++) {
                acc[ct] = __builtin_amdgcn_mfma_f32_16x16x32_bf16(al[kk], wfh[kk][ct], acc[ct], 0, 0, 0);
                acc[ct] = __builtin_amdgcn_mfma_f32_16x16x32_bf16(ah[kk], wfl[kk][ct], acc[ct], 0, 0, 0);
                acc[ct] = __builtin_amdgcn_mfma_f32_16x16x32_bf16(ah[kk], wfh[kk][ct], acc[ct], 0, 0, 0);
            }
        }

#pragma unroll
        for (int ct = 0; ct < 4; ct++)
#pragma unroll
            for (int i = 0; i < 4; i++) {
                size_t row = (size_t)(tile << 4) + quad * 4 + i;
                float val = fmaxf(acc[ct][i] + bv[ct], 0.f);
                outp[row * 64 + ct * 16 + m] = val;
                ssum[ct] += (double)val;
                ssq[ct]  += (double)val * (double)val;
            }
    }

#pragma unroll
    for (int ct = 0; ct < 4; ct++) {
        double sv = ssum[ct], qv = ssq[ct];
        sv += __shfl_xor(sv, 16, 64); sv += __shfl_xor(sv, 32, 64);
        qv += __shfl_xor(qv, 16, 64); qv += __shfl_xor(qv, 32, 64);
        if (quad == 0) {
            atomAddD(&stats_raw[ct * 16 + m], sv);
            atomAddD(&stats_raw[64 + ct * 16 + m], qv);
        }
    }
}

// out = relu(bn(out_pre; stats4, g3, be3)) -> f32
__global__ void k_out(const float* __restrict__ op, const float* __restrict__ fin,
                      const float* __restrict__ g, const float* __restrict__ be,
                      float* __restrict__ out) {
    int i = blockIdx.x * 256 + threadIdx.x;   // covers NN*64 exactly
    int c = i & 63;
    out[i] = fmaxf((op[i] - fin[c]) * fin[64 + c] * g[c] + be[c], 0.f);
}

extern "C" void kernel_launch(void* const* d_in, const int* in_sizes, int n_in,
                              void* d_out, int out_size, void* d_ws, size_t ws_size,
                              hipStream_t stream) {
    const float* x    = (const float*)d_in[0];
    const int*   ei   = (const int*)d_in[1];
    const float* W_un = (const float*)d_in[2];
    const float* b_un = (const float*)d_in[3];
    const float* g1   = (const float*)d_in[4];
    const float* be1  = (const float*)d_in[5];
    const float* W_gc = (const float*)d_in[6];
    const float* b_gc = (const float*)d_in[7];
    const float* g2   = (const float*)d_in[8];
    const float* be2  = (const float*)d_in[9];
    const float* W_tr = (const float*)d_in[10];
    const float* b_tr = (const float*)d_in[11];
    const float* W_li = (const float*)d_in[12];
    const float* b_li = (const float*)d_in[13];
    const float* g3   = (const float*)d_in[14];
    const float* be3  = (const float*)d_in[15];

    float* ws = (float*)d_ws;
    const size_t FN = (size_t)NN * 64;           // 3.2M floats (12.8 MB)
    const size_t FR = (size_t)RR * 64;           // 54.4M floats (217.6 MB)
    // Slot plan (liveness-packed, total ~256.4 MB < 256 MiB):
    //  P0: u            -> agg (zeroed post-ph0) -> (dead)
    //  P1: v            -> tpre
    //  P2: msg          -> outpre
    //  H : [s_tab | dsum | u2 | ...free...] early -> h2pre (all R rows) after k_msg
    //  tail: stats_raw f64[512] | od i32[N] | id i32[N] | stats_fin f32[512]
    float*  P0 = ws;
    float*  P1 = ws + FN;
    float*  P2 = ws + 2 * FN;
    float*  H  = ws + 3 * FN;
    float*  u      = P0;
    float*  v      = P1;
    float*  msg    = P2;
    float*  s_tab  = H;
    float*  dsum   = H + FN;
    float*  u2     = H + 2 * FN;
    float*  h2pre  = H;
    float*  agg    = P0;
    float*  tpre   = P1;
    float*  outpre = P2;
    double* stats_raw = (double*)(H + FR);
    int*    od        = (int*)(stats_raw + 512);
    int*    id        = od + NN;
    float*  stats_fin = (float*)(id + NN);

    // zeros: s_tab, msg, stats_raw+od+id
    hipMemsetAsync(s_tab, 0, FN * sizeof(float), stream);
    hipMemsetAsync(msg,   0, FN * sizeof(float), stream);
    hipMemsetAsync(stats_raw, 0, 512 * sizeof(double) + 2 * NN * sizeof(int), stream);

    // stage 0
    k_copy_x   <<<12500,  256, 0, stream>>>(x, dsum);
    k_edge_dsum<<<200000, 256, 0, stream>>>(x, ei, dsum);
    k_deg      <<<3125,   256, 0, stream>>>(ei, od, id);

    // per-node tables
    k_uv3<<<512, 256, 0, stream>>>(x, dsum, W_un, u, v, u2);

    // stage-1 stats (analytic, per-node only) + scatter
    k_stats1a<<<256, 256, 0, stream>>>(u, v, u2, od, id, stats_raw + 0);
    k_fin1<<<1, 64, 0, stream>>>(stats_raw + 0, b_un, stats_fin + 0, 1.0 / (double)RR);
    k_s1<<<212500, 256, 0, stream>>>(u, v, b_un, ei, stats_fin + 0, g1, be1, s_tab);
    k_msg<<<200000, 256, 0, stream>>>(ei, s_tab, msg);

    // stage-2: one gather pass (stats + h2pre store), then streaming scatter
    k_ph0<<<2048, 256, 0, stream>>>(u, v, msg, ei, W_gc, b_un, b_gc,
                                    stats_fin + 0, g1, be1, h2pre, stats_raw + 128);
    k_fin<<<1, 64, 0, stream>>>(stats_raw + 128, stats_fin + 128, 1.0 / (double)RR);
    hipMemsetAsync(agg, 0, FN * sizeof(float), stream);
    k_scatter2<<<212500, 256, 0, stream>>>(h2pre, ei, stats_fin + 128, g2, be2, agg);

    // stage 3
    k_mm3<<<512, 256, 0, stream>>>(h2pre, agg, W_tr, b_tr, stats_fin + 128, g2, be2,
                                   tpre, stats_raw + 256);
    k_fin<<<1, 64, 0, stream>>>(stats_raw + 256, stats_fin + 256, 1.0 / (double)NN);

    // stage 4
    k_mm4<<<512, 256, 0, stream>>>(tpre, W_li, b_li, stats_fin + 256, g2, be2,
                                   outpre, stats_raw + 384);
    k_fin<<<1, 64, 0, stream>>>(stats_raw + 384, stats_fin + 384, 1.0 / (double)NN);

    k_out<<<12500, 256, 0, stream>>>(outpre, stats_fin + 384, g3, be3, (float*)d_out);
}

// Round 9
// 1373.287 us; speedup vs baseline: 1.5668x; 1.1658x over previous
//
#include <hip/hip_runtime.h>
#include <cstdint>
#include <math.h>

// Problem sizes (fixed by the reference).
#define NN 50000
#define EE 800000
#define RR 850000      // NN + EE rows
#define NT_N 3125      // NN/16
#define NT_R 53125     // RR/16

typedef short  bf16x8 __attribute__((ext_vector_type(8)));
typedef float  f32x4  __attribute__((ext_vector_type(4)));

__device__ __forceinline__ float bf2f(unsigned short b) {
    unsigned int u = ((unsigned int)b) << 16;
    return __builtin_bit_cast(float, u);
}
__device__ __forceinline__ unsigned short f2bf(float f) {
    unsigned int u = __builtin_bit_cast(unsigned int, f);
    u = u + 0x7fffu + ((u >> 16) & 1u);
    return (unsigned short)(u >> 16);
}
__device__ __forceinline__ void atomAddF(float* p, float v) { unsafeAtomicAdd(p, v); }
__device__ __forceinline__ void atomAddD(double* p, double v) { unsafeAtomicAdd(p, v); }
__device__ __forceinline__ int atomAddI(int* p, int v) { return atomicAdd(p, v); }

// split 8 consecutive f32 into hi/lo bf16 fragments: hi+lo == v to ~2^-16 rel
__device__ __forceinline__ void split8(const float* p, bf16x8& hi, bf16x8& lo) {
    f32x4 v0 = *reinterpret_cast<const f32x4*>(p);
    f32x4 v1 = *reinterpret_cast<const f32x4*>(p + 4);
#pragma unroll
    for (int j = 0; j < 4; j++) {
        unsigned short h0 = f2bf(v0[j]);
        hi[j] = (short)h0; lo[j] = (short)f2bf(v0[j] - bf2f(h0));
        unsigned short h1 = f2bf(v1[j]);
        hi[4 + j] = (short)h1; lo[4 + j] = (short)f2bf(v1[j] - bf2f(h1));
    }
}
__device__ __forceinline__ void split8r(const float* v, bf16x8& hi, bf16x8& lo) {
#pragma unroll
    for (int j = 0; j < 8; j++) {
        unsigned short h = f2bf(v[j]);
        hi[j] = (short)h; lo[j] = (short)f2bf(v[j] - bf2f(h));
    }
}

// LDS-staged coalesced tile store: MFMA C-layout -> 4x 1KB contiguous dwordx4 stores.
// wl: per-wave LDS of 16*68 floats (pad 68 keeps writes ~2-way, reads 16B-aligned).
template <bool RELU, bool STATS>
__device__ __forceinline__ void epi_tile(float* wl, int lane, const f32x4* acc,
                                         const float* bv, float* __restrict__ gout,
                                         int tile, double* ssum, double* ssq) {
    const int m = lane & 15, quad = lane >> 4;
#pragma unroll
    for (int ct = 0; ct < 4; ct++)
#pragma unroll
        for (int i = 0; i < 4; i++) {
            float val = acc[ct][i] + bv[ct];
            if (RELU) val = fmaxf(val, 0.f);
            wl[(quad * 4 + i) * 68 + ct * 16 + m] = val;
            if (STATS) { ssum[ct] += (double)val; ssq[ct] += (double)val * (double)val; }
        }
    asm volatile("s_waitcnt lgkmcnt(0)" ::: "memory");
#pragma unroll
    for (int j = 0; j < 4; j++) {
        int row = j * 4 + quad;
        f32x4 vv = *reinterpret_cast<const f32x4*>(wl + row * 68 + m * 4);
        *reinterpret_cast<f32x4*>(gout + ((size_t)(tile << 4) + row) * 64 + m * 4) = vv;
    }
}

// ---------- degree counts ----------
__global__ void k_deg(const int* __restrict__ ei, int* __restrict__ od, int* __restrict__ id) {
    int e = blockIdx.x * 256 + threadIdx.x;   // covers EE exactly
    atomAddI(&od[ei[e]], 1);
    atomAddI(&id[ei[EE + e]], 1);
}

// ---------- exclusive scan of in-degree -> off, cursor (single block) ----------
__global__ void __launch_bounds__(1024) k_scan(const int* __restrict__ cnt,
                                               int* __restrict__ off, int* __restrict__ cursor) {
    __shared__ int part[1024];
    const int t = threadIdx.x;
    const int CH = (NN + 1023) / 1024;   // 49
    int base = t * CH, s = 0;
    for (int i = 0; i < CH; i++) { int idx = base + i; if (idx < NN) s += cnt[idx]; }
    part[t] = s;
    __syncthreads();
    if (t == 0) {
        int run = 0;
        for (int i = 0; i < 1024; i++) { int x = part[i]; part[i] = run; run += x; }
    }
    __syncthreads();
    int run = part[t];
    for (int i = 0; i < CH; i++) {
        int idx = base + i;
        if (idx < NN) { off[idx] = run; cursor[idx] = run; run += cnt[idx]; }
    }
    if (t == 0) off[NN] = EE;
}

// ---------- fill dst-sorted edge arrays ----------
__global__ void k_fill(const int* __restrict__ ei, int* __restrict__ cursor,
                       int* __restrict__ srcs_s, int* __restrict__ dsts_s) {
    int e = blockIdx.x * 256 + threadIdx.x;   // covers EE exactly
    int d = ei[EE + e];
    int p = atomAddI(&cursor[d], 1);          // old value = fill position
    srcs_s[p] = ei[e];
    dsts_s[p] = d;
}

// ---------- dsum[n] = x[n] + sum_{e: dst=n} x[src_e]  (CSR, no atomics) ----------
__global__ void k_dsum_csr(const float* __restrict__ x, const int* __restrict__ off,
                           const int* __restrict__ srcs, float* __restrict__ dsum) {
    int team = (blockIdx.x * 256 + threadIdx.x) >> 6;   // 12500 blocks x 4 = NN
    int c = threadIdx.x & 63;
    float a0 = x[(size_t)team * 64 + c], a1 = 0.f;
    int e = off[team], e1 = off[team + 1];
    for (; e + 1 < e1; e += 2) {
        a0 += x[(size_t)srcs[e] * 64 + c];
        a1 += x[(size_t)srcs[e + 1] * 64 + c];
    }
    if (e < e1) a0 += x[(size_t)srcs[e] * 64 + c];
    dsum[(size_t)team * 64 + c] = a0 + a1;
}

// ---------- u = x@W_top, v = dsum@W_bot, u2 = dsum@W_top ----------
__global__ void k_uv3(const float* __restrict__ x, const float* __restrict__ dsum,
                      const float* __restrict__ W, float* __restrict__ u,
                      float* __restrict__ v, float* __restrict__ u2) {
    __shared__ float lds[4][16 * 68];
    const int lane = threadIdx.x & 63;
    const int wid = threadIdx.x >> 6;
    const int m = lane & 15, quad = lane >> 4;
    const int gwave = (blockIdx.x * blockDim.x + threadIdx.x) >> 6;
    const int nwaves = (gridDim.x * blockDim.x) >> 6;
    float* wl = lds[wid];

    bf16x8 wfh[4][4], wfl[4][4];
#pragma unroll
    for (int kk = 0; kk < 4; kk++)
#pragma unroll
        for (int ct = 0; ct < 4; ct++) {
            float wv[8];
#pragma unroll
            for (int j = 0; j < 8; j++)
                wv[j] = W[(kk * 32 + quad * 8 + j) * 64 + ct * 16 + m];
            split8r(wv, wfh[kk][ct], wfl[kk][ct]);
        }
    float zb[4] = {0.f, 0.f, 0.f, 0.f};

    for (int tile = gwave; tile < NT_N; tile += nwaves) {
        const int r = (tile << 4) + m;
        bf16x8 ah[4], al[4];
        split8(x    + (size_t)r * 64 + quad * 8,      ah[0], al[0]);
        split8(x    + (size_t)r * 64 + 32 + quad * 8, ah[1], al[1]);
        split8(dsum + (size_t)r * 64 + quad * 8,      ah[2], al[2]);
        split8(dsum + (size_t)r * 64 + 32 + quad * 8, ah[3], al[3]);

        f32x4 zero = {0.f, 0.f, 0.f, 0.f};
        f32x4 aU[4], aV[4], aU2[4];
#pragma unroll
        for (int ct = 0; ct < 4; ct++) {
            aU[ct] = zero; aV[ct] = zero; aU2[ct] = zero;
#pragma unroll
            for (int kk = 0; kk < 2; kk++) {
                aU[ct]  = __builtin_amdgcn_mfma_f32_16x16x32_bf16(al[kk],   wfh[kk][ct],   aU[ct],  0, 0, 0);
                aU[ct]  = __builtin_amdgcn_mfma_f32_16x16x32_bf16(ah[kk],   wfl[kk][ct],   aU[ct],  0, 0, 0);
                aU[ct]  = __builtin_amdgcn_mfma_f32_16x16x32_bf16(ah[kk],   wfh[kk][ct],   aU[ct],  0, 0, 0);
                aV[ct]  = __builtin_amdgcn_mfma_f32_16x16x32_bf16(al[kk+2], wfh[kk+2][ct], aV[ct],  0, 0, 0);
                aV[ct]  = __builtin_amdgcn_mfma_f32_16x16x32_bf16(ah[kk+2], wfl[kk+2][ct], aV[ct],  0, 0, 0);
                aV[ct]  = __builtin_amdgcn_mfma_f32_16x16x32_bf16(ah[kk+2], wfh[kk+2][ct], aV[ct],  0, 0, 0);
                aU2[ct] = __builtin_amdgcn_mfma_f32_16x16x32_bf16(al[kk+2], wfh[kk][ct],   aU2[ct], 0, 0, 0);
                aU2[ct] = __builtin_amdgcn_mfma_f32_16x16x32_bf16(ah[kk+2], wfl[kk][ct],   aU2[ct], 0, 0, 0);
                aU2[ct] = __builtin_amdgcn_mfma_f32_16x16x32_bf16(ah[kk+2], wfh[kk][ct],   aU2[ct], 0, 0, 0);
            }
        }
        epi_tile<false, false>(wl, lane, aU,  zb, u,  tile, nullptr, nullptr);
        epi_tile<false, false>(wl, lane, aV,  zb, v,  tile, nullptr, nullptr);
        epi_tile<false, false>(wl, lane, aU2, zb, u2, tile, nullptr, nullptr);
    }
}

// ---------- analytic stage-1 stats ----------
__global__ void k_stats1a(const float* __restrict__ u, const float* __restrict__ v,
                          const float* __restrict__ u2, const int* __restrict__ od,
                          const int* __restrict__ id, double* __restrict__ stats_raw) {
    __shared__ double lsum[4][64], lsq[4][64];
    int tid = threadIdx.x, c = tid & 63, w = tid >> 6;
    double a1 = 0.0, a2 = 0.0;
    for (int n = blockIdx.x * 4 + w; n < NN; n += gridDim.x * 4) {
        double uu = u[(size_t)n * 64 + c], vv = v[(size_t)n * 64 + c];
        double uu2 = u2[(size_t)n * 64 + c];
        double wod = 1.0 + od[n], wid = 1.0 + id[n];
        a1 += wod * uu + wid * vv;
        a2 += wod * uu * uu + wid * vv * vv + 2.0 * vv * uu2;
    }
    lsum[w][c] = a1; lsq[w][c] = a2;
    __syncthreads();
    if (w == 0) {
        a1 = lsum[0][c] + lsum[1][c] + lsum[2][c] + lsum[3][c];
        a2 = lsq[0][c] + lsq[1][c] + lsq[2][c] + lsq[3][c];
        atomAddD(&stats_raw[c], a1);
        atomAddD(&stats_raw[64 + c], a2);
    }
}

__global__ void k_fin1(const double* __restrict__ raw, const float* __restrict__ b,
                       float* __restrict__ fin, double inv_cnt) {
    int c = threadIdx.x;
    double m1 = raw[c] * inv_cnt;
    double var = raw[64 + c] * inv_cnt - m1 * m1;
    if (var < 0.0) var = 0.0;
    fin[c] = (float)(m1 + (double)b[c]);
    fin[64 + c] = (float)(1.0 / sqrt(var + 1e-5));
}

__global__ void k_fin(const double* __restrict__ raw, float* __restrict__ fin, double inv_cnt) {
    int c = threadIdx.x;
    double mean = raw[c] * inv_cnt;
    double var = raw[64 + c] * inv_cnt - mean * mean;
    if (var < 0.0) var = 0.0;
    fin[c] = (float)mean;
    fin[64 + c] = (float)(1.0 / sqrt(var + 1e-5));
}

// ---------- s_tab[n] = relu(bn1(u[n]+v[n]+b)) + sum_{e:dst=n} relu(bn1(u[src]+v[n]+b)) ----------
__global__ void k_s1_csr(const float* __restrict__ u, const float* __restrict__ v,
                         const int* __restrict__ off, const int* __restrict__ srcs,
                         const float* __restrict__ b_un, const float* __restrict__ fin,
                         const float* __restrict__ g1, const float* __restrict__ be1,
                         float* __restrict__ s_tab) {
    int team = (blockIdx.x * 256 + threadIdx.x) >> 6;
    int c = threadIdx.x & 63;
    float sc = fin[64 + c] * g1[c];
    float tsh = (b_un[c] - fin[c]) * sc + be1[c];
    float vn = v[(size_t)team * 64 + c];
    float a0 = fmaxf((u[(size_t)team * 64 + c] + vn) * sc + tsh, 0.f);   // self row
    float a1 = 0.f;
    int e = off[team], e1 = off[team + 1];
    for (; e + 1 < e1; e += 2) {
        a0 += fmaxf((u[(size_t)srcs[e] * 64 + c] + vn) * sc + tsh, 0.f);
        a1 += fmaxf((u[(size_t)srcs[e + 1] * 64 + c] + vn) * sc + tsh, 0.f);
    }
    if (e < e1) a0 += fmaxf((u[(size_t)srcs[e] * 64 + c] + vn) * sc + tsh, 0.f);
    s_tab[(size_t)team * 64 + c] = a0 + a1;
}

// ---------- msg[n] = sum_{e:dst=n} s_tab[src_e] ----------
__global__ void k_msg_csr(const int* __restrict__ off, const int* __restrict__ srcs,
                          const float* __restrict__ s_tab, float* __restrict__ msg) {
    int team = (blockIdx.x * 256 + threadIdx.x) >> 6;
    int c = threadIdx.x & 63;
    float a0 = 0.f, a1 = 0.f;
    int e = off[team], e1 = off[team + 1];
    for (; e + 1 < e1; e += 2) {
        a0 += s_tab[(size_t)srcs[e] * 64 + c];
        a1 += s_tab[(size_t)srcs[e + 1] * 64 + c];
    }
    if (e < e1) a0 += s_tab[(size_t)srcs[e] * 64 + c];
    msg[(size_t)team * 64 + c] = a0 + a1;
}

// ---------- stage-2: h2_pre[row] = [relu(bn1(u[sr]+v[dm]+b_un)), msg[dm]] @ W_gc + b_gc
// Edge rows in dst-sorted order (v/msg gathers are near-uniform per tile).
__global__ void k_ph0(const float* __restrict__ u, const float* __restrict__ v,
                      const float* __restrict__ msg, const int* __restrict__ srcs_s,
                      const int* __restrict__ dsts_s,
                      const float* __restrict__ W, const float* __restrict__ b_un,
                      const float* __restrict__ b_gc,
                      const float* __restrict__ fin1, const float* __restrict__ g1,
                      const float* __restrict__ be1,
                      float* __restrict__ h2pre, double* __restrict__ stats_raw) {
    __shared__ float lds[4][16 * 68];
    const int lane = threadIdx.x & 63;
    const int wid = threadIdx.x >> 6;
    const int m = lane & 15, quad = lane >> 4;
    const int gwave = (blockIdx.x * blockDim.x + threadIdx.x) >> 6;
    const int nwaves = (gridDim.x * blockDim.x) >> 6;
    float* wl = lds[wid];

    bf16x8 wfh[4][4], wfl[4][4];
#pragma unroll
    for (int kk = 0; kk < 4; kk++)
#pragma unroll
        for (int ct = 0; ct < 4; ct++) {
            float wv[8];
#pragma unroll
            for (int j = 0; j < 8; j++)
                wv[j] = W[(kk * 32 + quad * 8 + j) * 64 + ct * 16 + m];
            split8r(wv, wfh[kk][ct], wfl[kk][ct]);
        }

    float bv[4];
#pragma unroll
    for (int ct = 0; ct < 4; ct++) bv[ct] = b_gc[ct * 16 + m];

    float s1f[2][8], t1f[2][8];
#pragma unroll
    for (int kk = 0; kk < 2; kk++)
#pragma unroll
        for (int j = 0; j < 8; j++) {
            int c = kk * 32 + quad * 8 + j;
            float sc = fin1[64 + c] * g1[c];
            s1f[kk][j] = sc;
            t1f[kk][j] = be1[c] + (b_un[c] - fin1[c]) * sc;
        }

    double ssum[4] = {0,0,0,0}, ssq[4] = {0,0,0,0};

    for (int tile = gwave; tile < NT_R; tile += nwaves) {
        const int r = (tile << 4) + m;
        const bool selftile = (tile < NT_N);
        int sr = selftile ? r : srcs_s[r - NN];
        int dm = selftile ? r : dsts_s[r - NN];

        bf16x8 ah[4], al[4];
#pragma unroll
        for (int kk = 0; kk < 2; kk++) {
            f32x4 u0 = *reinterpret_cast<const f32x4*>(u + (size_t)sr * 64 + kk * 32 + quad * 8);
            f32x4 u1 = *reinterpret_cast<const f32x4*>(u + (size_t)sr * 64 + kk * 32 + quad * 8 + 4);
            f32x4 v0 = *reinterpret_cast<const f32x4*>(v + (size_t)dm * 64 + kk * 32 + quad * 8);
            f32x4 v1 = *reinterpret_cast<const f32x4*>(v + (size_t)dm * 64 + kk * 32 + quad * 8 + 4);
            float tv[8];
#pragma unroll
            for (int j = 0; j < 4; j++) {
                tv[j]     = fmaxf((u0[j] + v0[j]) * s1f[kk][j]     + t1f[kk][j],     0.f);
                tv[4 + j] = fmaxf((u1[j] + v1[j]) * s1f[kk][4 + j] + t1f[kk][4 + j], 0.f);
            }
            split8r(tv, ah[kk], al[kk]);
            split8(msg + (size_t)dm * 64 + kk * 32 + quad * 8, ah[2 + kk], al[2 + kk]);
        }

        f32x4 zero = {0.f, 0.f, 0.f, 0.f};
        f32x4 acc[4];
#pragma unroll
        for (int ct = 0; ct < 4; ct++) {
            acc[ct] = zero;
#pragma unroll
            for (int kk = 0; kk < 4; kk++)
                acc[ct] = __builtin_amdgcn_mfma_f32_16x16x32_bf16(al[kk], wfh[kk][ct], acc[ct], 0, 0, 0);
#pragma unroll
            for (int kk = 0; kk < 4; kk++)
                acc[ct] = __builtin_amdgcn_mfma_f32_16x16x32_bf16(ah[kk], wfl[kk][ct], acc[ct], 0, 0, 0);
#pragma unroll
            for (int kk = 0; kk < 4; kk++)
                acc[ct] = __builtin_amdgcn_mfma_f32_16x16x32_bf16(ah[kk], wfh[kk][ct], acc[ct], 0, 0, 0);
        }

        epi_tile<false, true>(wl, lane, acc, bv, h2pre, tile, ssum, ssq);
    }

#pragma unroll
    for (int ct = 0; ct < 4; ct++) {
        double sv = ssum[ct], qv = ssq[ct];
        sv += __shfl_xor(sv, 16, 64); sv += __shfl_xor(sv, 32, 64);
        qv += __shfl_xor(qv, 16, 64); qv += __shfl_xor(qv, 32, 64);
        if (quad == 0) {
            atomAddD(&stats_raw[ct * 16 + m], sv);
            atomAddD(&stats_raw[64 + ct * 16 + m], qv);
        }
    }
}

// ---------- stage-2 scatter: stream h2_pre, agg[src] += relu(bn2(h2_pre)) ----------
__global__ void k_scatter2(const float* __restrict__ h2pre, const int* __restrict__ srcs_s,
                           const float* __restrict__ fin2, const float* __restrict__ g2,
                           const float* __restrict__ be2, float* __restrict__ agg) {
    size_t i = (size_t)blockIdx.x * 256 + threadIdx.x;   // covers RR*64 exactly
    int r = (int)(i >> 6), c = (int)(i & 63);
    float sc = fin2[64 + c] * g2[c];
    float h2n = fmaxf((h2pre[i] - fin2[c]) * sc + be2[c], 0.f);
    int sr = (r < NN) ? r : srcs_s[r - NN];
    atomAddF(&agg[(size_t)sr * 64 + c], h2n);
}

// ---------- stage 3: t_pre = [relu(bn2(h2pre[:N])), agg] @ W_tr + b_tr, stats3 ----------
__global__ void k_mm3(const float* __restrict__ h2pre, const float* __restrict__ agg,
                      const float* __restrict__ W, const float* __restrict__ bias,
                      const float* __restrict__ fin2, const float* __restrict__ g2,
                      const float* __restrict__ be2,
                      float* __restrict__ outp, double* __restrict__ stats_raw) {
    __shared__ float lds[4][16 * 68];
    const int lane = threadIdx.x & 63;
    const int wid = threadIdx.x >> 6;
    const int m = lane & 15, quad = lane >> 4;
    const int gwave = (blockIdx.x * blockDim.x + threadIdx.x) >> 6;
    const int nwaves = (gridDim.x * blockDim.x) >> 6;
    float* wl = lds[wid];

    bf16x8 wfh[4][4], wfl[4][4];
#pragma unroll
    for (int kk = 0; kk < 4; kk++)
#pragma unroll
        for (int ct = 0; ct < 4; ct++) {
            float wv[8];
#pragma unroll
            for (int j = 0; j < 8; j++)
                wv[j] = W[(kk * 32 + quad * 8 + j) * 64 + ct * 16 + m];
            split8r(wv, wfh[kk][ct], wfl[kk][ct]);
        }

    float bv[4];
#pragma unroll
    for (int ct = 0; ct < 4; ct++) bv[ct] = bias[ct * 16 + m];

    float s2f[2][8], t2f[2][8];
#pragma unroll
    for (int kk = 0; kk < 2; kk++)
#pragma unroll
        for (int j = 0; j < 8; j++) {
            int c = kk * 32 + quad * 8 + j;
            float sc = fin2[64 + c] * g2[c];
            s2f[kk][j] = sc;
            t2f[kk][j] = be2[c] - fin2[c] * sc;
        }

    double ssum[4] = {0,0,0,0}, ssq[4] = {0,0,0,0};

    for (int tile = gwave; tile < NT_N; tile += nwaves) {
        const int r = (tile << 4) + m;
        bf16x8 ah[4], al[4];
#pragma unroll
        for (int kk = 0; kk < 2; kk++) {
            f32x4 v0 = *reinterpret_cast<const f32x4*>(h2pre + (size_t)r * 64 + kk * 32 + quad * 8);
            f32x4 v1 = *reinterpret_cast<const f32x4*>(h2pre + (size_t)r * 64 + kk * 32 + quad * 8 + 4);
            float tv[8];
#pragma unroll
            for (int j = 0; j < 4; j++) {
                tv[j]     = fmaxf(v0[j] * s2f[kk][j]     + t2f[kk][j],     0.f);
                tv[4 + j] = fmaxf(v1[j] * s2f[kk][4 + j] + t2f[kk][4 + j], 0.f);
            }
            split8r(tv, ah[kk], al[kk]);
        }
        split8(agg + (size_t)r * 64 + quad * 8,      ah[2], al[2]);
        split8(agg + (size_t)r * 64 + 32 + quad * 8, ah[3], al[3]);

        f32x4 zero = {0.f, 0.f, 0.f, 0.f};
        f32x4 acc[4];
#pragma unroll
        for (int ct = 0; ct < 4; ct++) {
            acc[ct] = zero;
#pragma unroll
            for (int kk = 0; kk < 4; kk++)
                acc[ct] = __builtin_amdgcn_mfma_f32_16x16x32_bf16(al[kk], wfh[kk][ct], acc[ct], 0, 0, 0);
#pragma unroll
            for (int kk = 0; kk < 4; kk++)
                acc[ct] = __builtin_amdgcn_mfma_f32_16x16x32_bf16(ah[kk], wfl[kk][ct], acc[ct], 0, 0, 0);
#pragma unroll
            for (int kk = 0; kk < 4; kk++)
                acc[ct] = __builtin_amdgcn_mfma_f32_16x16x32_bf16(ah[kk], wfh[kk][ct], acc[ct], 0, 0, 0);
        }

        epi_tile<false, true>(wl, lane, acc, bv, outp, tile, ssum, ssq);
    }

#pragma unroll
    for (int ct = 0; ct < 4; ct++) {
        double sv = ssum[ct], qv = ssq[ct];
        sv += __shfl_xor(sv, 16, 64); sv += __shfl_xor(sv, 32, 64);
        qv += __shfl_xor(qv, 16, 64); qv += __shfl_xor(qv, 32, 64);
        if (quad == 0) {
            atomAddD(&stats_raw[ct * 16 + m], sv);
            atomAddD(&stats_raw[64 + ct * 16 + m], qv);
        }
    }
}

// ---------- stage 4 ----------
__global__ void k_mm4(const float* __restrict__ tpre, const float* __restrict__ W,
                      const float* __restrict__ bias, const float* __restrict__ fin3,
                      const float* __restrict__ g2, const float* __restrict__ be2,
                      float* __restrict__ outp, double* __restrict__ stats_raw) {
    __shared__ float lds[4][16 * 68];
    const int lane = threadIdx.x & 63;
    const int wid = threadIdx.x >> 6;
    const int m = lane & 15, quad = lane >> 4;
    const int gwave = (blockIdx.x * blockDim.x + threadIdx.x) >> 6;
    const int nwaves = (gridDim.x * blockDim.x) >> 6;
    float* wl = lds[wid];

    bf16x8 wfh[2][4], wfl[2][4];
#pragma unroll
    for (int kk = 0; kk < 2; kk++)
#pragma unroll
        for (int ct = 0; ct < 4; ct++) {
            float wv[8];
#pragma unroll
            for (int j = 0; j < 8; j++)
                wv[j] = W[(kk * 32 + quad * 8 + j) * 64 + ct * 16 + m];
            split8r(wv, wfh[kk][ct], wfl[kk][ct]);
        }

    float bv[4];
#pragma unroll
    for (int ct = 0; ct < 4; ct++) bv[ct] = bias[ct * 16 + m];

    float sc[2][8], sh[2][8];
#pragma unroll
    for (int kk = 0; kk < 2; kk++)
#pragma unroll
        for (int j = 0; j < 8; j++) {
            int c = kk * 32 + quad * 8 + j;
            float s = fin3[64 + c] * g2[c];
            sc[kk][j] = s;
            sh[kk][j] = be2[c] - fin3[c] * s;
        }

    double ssum[4] = {0,0,0,0}, ssq[4] = {0,0,0,0};

    for (int tile = gwave; tile < NT_N; tile += nwaves) {
        const int r = (tile << 4) + m;
        bf16x8 ah[2], al[2];
#pragma unroll
        for (int kk = 0; kk < 2; kk++) {
            f32x4 v0 = *reinterpret_cast<const f32x4*>(tpre + (size_t)r * 64 + kk * 32 + quad * 8);
            f32x4 v1 = *reinterpret_cast<const f32x4*>(tpre + (size_t)r * 64 + kk * 32 + quad * 8 + 4);
            float tv[8];
#pragma unroll
            for (int j = 0; j < 4; j++) {
                tv[j]     = fmaxf(v0[j] * sc[kk][j]     + sh[kk][j],     0.f);
                tv[4 + j] = fmaxf(v1[j] * sc[kk][4 + j] + sh[kk][4 + j], 0.f);
            }
            split8r(tv, ah[kk], al[kk]);
        }

        f32x4 zero = {0.f, 0.f, 0.f, 0.f};
        f32x4 acc[4];
#pragma unroll
        for (int ct = 0; ct < 4; ct++) {
            acc[ct] = zero;
#pragma unroll
            for (int kk = 0; kk < 2; kk++) {
                acc[ct] = __builtin_amdgcn_mfma_f32_16x16x32_bf16(al[kk], wfh[kk][ct], acc[ct], 0, 0, 0);
                acc[ct] = __builtin_amdgcn_mfma_f32_16x16x32_bf16(ah[kk], wfl[kk][ct], acc[ct], 0, 0, 0);
                acc[ct] = __builtin_amdgcn_mfma_f32_16x16x32_bf16(ah[kk], wfh[kk][ct], acc[ct], 0, 0, 0);
            }
        }

        epi_tile<true, true>(wl, lane, acc, bv, outp, tile, ssum, ssq);
    }

#pragma unroll
    for (int ct = 0; ct < 4; ct++) {
        double sv = ssum[ct], qv = ssq[ct];
        sv += __shfl_xor(sv, 16, 64); sv += __shfl_xor(sv, 32, 64);
        qv += __shfl_xor(qv, 16, 64); qv += __shfl_xor(qv, 32, 64);
        if (quad == 0) {
            atomAddD(&stats_raw[ct * 16 + m], sv);
            atomAddD(&stats_raw[64 + ct * 16 + m], qv);
        }
    }
}

// out = relu(bn(out_pre; stats4, g3, be3)) -> f32
__global__ void k_out(const float* __restrict__ op, const float* __restrict__ fin,
                      const float* __restrict__ g, const float* __restrict__ be,
                      float* __restrict__ out) {
    int i = blockIdx.x * 256 + threadIdx.x;   // covers NN*64 exactly
    int c = i & 63;
    out[i] = fmaxf((op[i] - fin[c]) * fin[64 + c] * g[c] + be[c], 0.f);
}

extern "C" void kernel_launch(void* const* d_in, const int* in_sizes, int n_in,
                              void* d_out, int out_size, void* d_ws, size_t ws_size,
                              hipStream_t stream) {
    const float* x    = (const float*)d_in[0];
    const int*   ei   = (const int*)d_in[1];
    const float* W_un = (const float*)d_in[2];
    const float* b_un = (const float*)d_in[3];
    const float* g1   = (const float*)d_in[4];
    const float* be1  = (const float*)d_in[5];
    const float* W_gc = (const float*)d_in[6];
    const float* b_gc = (const float*)d_in[7];
    const float* g2   = (const float*)d_in[8];
    const float* be2  = (const float*)d_in[9];
    const float* W_tr = (const float*)d_in[10];
    const float* b_tr = (const float*)d_in[11];
    const float* W_li = (const float*)d_in[12];
    const float* b_li = (const float*)d_in[13];
    const float* g3   = (const float*)d_in[14];
    const float* be3  = (const float*)d_in[15];

    float* ws = (float*)d_ws;
    const size_t FN = (size_t)NN * 64;           // 3.2M floats (12.8 MB)
    const size_t FR = (size_t)RR * 64;           // 54.4M floats (217.6 MB)
    // Slots:  P0: u -> agg     P1: v -> tpre     P2: msg -> outpre
    //         H : [s_tab | dsum | u2] early -> h2pre (R rows) after k_msg_csr
    //         tail: stats_raw f64[512] | od | id | off[NN+1] | cursor | srcs_s | dsts_s | stats_fin
    float*  P0 = ws;
    float*  P1 = ws + FN;
    float*  P2 = ws + 2 * FN;
    float*  H  = ws + 3 * FN;
    float*  u      = P0;
    float*  v      = P1;
    float*  msg    = P2;
    float*  s_tab  = H;
    float*  dsum   = H + FN;
    float*  u2     = H + 2 * FN;
    float*  h2pre  = H;
    float*  agg    = P0;
    float*  tpre   = P1;
    float*  outpre = P2;
    double* stats_raw = (double*)(H + FR);
    int*    od        = (int*)(stats_raw + 512);
    int*    id        = od + NN;
    int*    off       = id + NN;
    int*    cursor    = off + NN + 1;
    int*    srcs_s    = cursor + NN;
    int*    dsts_s    = srcs_s + EE;
    float*  stats_fin = (float*)(dsts_s + EE);

    // zero: stats_raw + od + id
    hipMemsetAsync(stats_raw, 0, 512 * sizeof(double) + 2 * NN * sizeof(int), stream);

    // build dst-sorted CSR
    k_deg <<<3125, 256,  0, stream>>>(ei, od, id);
    k_scan<<<1,    1024, 0, stream>>>(id, off, cursor);
    k_fill<<<3125, 256,  0, stream>>>(ei, cursor, srcs_s, dsts_s);

    // stage 0 + per-node tables
    k_dsum_csr<<<12500, 256, 0, stream>>>(x, off, srcs_s, dsum);
    k_uv3<<<512, 256, 0, stream>>>(x, dsum, W_un, u, v, u2);

    // stage-1: analytic stats, then CSR reductions (no data atomics)
    k_stats1a<<<256, 256, 0, stream>>>(u, v, u2, od, id, stats_raw + 0);
    k_fin1<<<1, 64, 0, stream>>>(stats_raw + 0, b_un, stats_fin + 0, 1.0 / (double)RR);
    k_s1_csr<<<12500, 256, 0, stream>>>(u, v, off, srcs_s, b_un, stats_fin + 0, g1, be1, s_tab);
    k_msg_csr<<<12500, 256, 0, stream>>>(off, srcs_s, s_tab, msg);

    // stage-2: one sorted gather pass (stats + h2pre), then streaming scatter
    k_ph0<<<2048, 256, 0, stream>>>(u, v, msg, srcs_s, dsts_s, W_gc, b_un, b_gc,
                                    stats_fin + 0, g1, be1, h2pre, stats_raw + 128);
    k_fin<<<1, 64, 0, stream>>>(stats_raw + 128, stats_fin + 128, 1.0 / (double)RR);
    hipMemsetAsync(agg, 0, FN * sizeof(float), stream);
    k_scatter2<<<212500, 256, 0, stream>>>(h2pre, srcs_s, stats_fin + 128, g2, be2, agg);

    // stage 3
    k_mm3<<<512, 256, 0, stream>>>(h2pre, agg, W_tr, b_tr, stats_fin + 128, g2, be2,
                                   tpre, stats_raw + 256);
    k_fin<<<1, 64, 0, stream>>>(stats_raw + 256, stats_fin + 256, 1.0 / (double)NN);

    // stage 4
    k_mm4<<<512, 256, 0, stream>>>(tpre, W_li, b_li, stats_fin + 256, g2, be2,
                                   outpre, stats_raw + 384);
    k_fin<<<1, 64, 0, stream>>>(stats_raw + 384, stats_fin + 384, 1.0 / (double)NN);

    k_out<<<12500, 256, 0, stream>>>(outpre, stats_fin + 384, g3, be3, (float*)d_out);
}

// Round 10
// 1243.362 us; speedup vs baseline: 1.7305x; 1.1045x over previous
//
#include <hip/hip_runtime.h>
#include <cstdint>
#include <math.h>

// Problem sizes (fixed by the reference).
#define NN 50000
#define EE 800000
#define RR 850000      // NN + EE rows
#define NT_N 3125      // NN/16
#define NT_R 53125     // RR/16

typedef short  bf16x8 __attribute__((ext_vector_type(8)));
typedef float  f32x4  __attribute__((ext_vector_type(4)));

__device__ __forceinline__ float bf2f(unsigned short b) {
    unsigned int u = ((unsigned int)b) << 16;
    return __builtin_bit_cast(float, u);
}
__device__ __forceinline__ unsigned short f2bf(float f) {
    unsigned int u = __builtin_bit_cast(unsigned int, f);
    u = u + 0x7fffu + ((u >> 16) & 1u);
    return (unsigned short)(u >> 16);
}
__device__ __forceinline__ void atomAddF(float* p, float v) { unsafeAtomicAdd(p, v); }
__device__ __forceinline__ void atomAddD(double* p, double v) { unsafeAtomicAdd(p, v); }
__device__ __forceinline__ int atomAddI(int* p, int v) { return atomicAdd(p, v); }

// split 8 consecutive f32 into hi/lo bf16 fragments: hi+lo == v to ~2^-16 rel
__device__ __forceinline__ void split8(const float* p, bf16x8& hi, bf16x8& lo) {
    f32x4 v0 = *reinterpret_cast<const f32x4*>(p);
    f32x4 v1 = *reinterpret_cast<const f32x4*>(p + 4);
#pragma unroll
    for (int j = 0; j < 4; j++) {
        unsigned short h0 = f2bf(v0[j]);
        hi[j] = (short)h0; lo[j] = (short)f2bf(v0[j] - bf2f(h0));
        unsigned short h1 = f2bf(v1[j]);
        hi[4 + j] = (short)h1; lo[4 + j] = (short)f2bf(v1[j] - bf2f(h1));
    }
}
__device__ __forceinline__ void split8r(const float* v, bf16x8& hi, bf16x8& lo) {
#pragma unroll
    for (int j = 0; j < 8; j++) {
        unsigned short h = f2bf(v[j]);
        hi[j] = (short)h; lo[j] = (short)f2bf(v[j] - bf2f(h));
    }
}

// LDS-staged coalesced tile store: MFMA C-layout -> 4x 1KB contiguous dwordx4 stores.
template <bool RELU, bool STATS>
__device__ __forceinline__ void epi_tile(float* wl, int lane, const f32x4* acc,
                                         const float* bv, float* __restrict__ gout,
                                         int tile, double* ssum, double* ssq) {
    const int m = lane & 15, quad = lane >> 4;
#pragma unroll
    for (int ct = 0; ct < 4; ct++)
#pragma unroll
        for (int i = 0; i < 4; i++) {
            float val = acc[ct][i] + bv[ct];
            if (RELU) val = fmaxf(val, 0.f);
            wl[(quad * 4 + i) * 68 + ct * 16 + m] = val;
            if (STATS) { ssum[ct] += (double)val; ssq[ct] += (double)val * (double)val; }
        }
    asm volatile("s_waitcnt lgkmcnt(0)" ::: "memory");
#pragma unroll
    for (int j = 0; j < 4; j++) {
        int row = j * 4 + quad;
        f32x4 vv = *reinterpret_cast<const f32x4*>(wl + row * 68 + m * 4);
        *reinterpret_cast<f32x4*>(gout + ((size_t)(tile << 4) + row) * 64 + m * 4) = vv;
    }
}

// ---------- degree counts ----------
__global__ void k_deg(const int* __restrict__ ei, int* __restrict__ od, int* __restrict__ id) {
    int e = blockIdx.x * 256 + threadIdx.x;   // covers EE exactly
    atomAddI(&od[ei[e]], 1);
    atomAddI(&id[ei[EE + e]], 1);
}

// ---------- exclusive scan of counts -> off, cursor (single block; generic) ----------
__global__ void __launch_bounds__(1024) k_scan(const int* __restrict__ cnt,
                                               int* __restrict__ off, int* __restrict__ cursor) {
    __shared__ int part[1024];
    const int t = threadIdx.x;
    const int CH = (NN + 1023) / 1024;   // 49
    int base = t * CH, s = 0;
    for (int i = 0; i < CH; i++) { int idx = base + i; if (idx < NN) s += cnt[idx]; }
    part[t] = s;
    __syncthreads();
    if (t == 0) {
        int run = 0;
        for (int i = 0; i < 1024; i++) { int x = part[i]; part[i] = run; run += x; }
    }
    __syncthreads();
    int run = part[t];
    for (int i = 0; i < CH; i++) {
        int idx = base + i;
        if (idx < NN) { off[idx] = run; cursor[idx] = run; run += cnt[idx]; }
    }
    if (t == 0) off[NN] = EE;
}

// ---------- fill dst-sorted edge arrays ----------
__global__ void k_fill(const int* __restrict__ ei, int* __restrict__ cursor,
                       int* __restrict__ srcs_s, int* __restrict__ dsts_s) {
    int e = blockIdx.x * 256 + threadIdx.x;   // covers EE exactly
    int d = ei[EE + e];
    int p = atomAddI(&cursor[d], 1);          // old value = fill position
    srcs_s[p] = ei[e];
    dsts_s[p] = d;
}

// ---------- fill src-CSR permutation: perm_s[q] = dst-order position p ----------
__global__ void k_fill2(const int* __restrict__ srcs_s, int* __restrict__ cursor_s,
                        int* __restrict__ perm_s) {
    int p = blockIdx.x * 256 + threadIdx.x;   // covers EE exactly
    int s = srcs_s[p];
    int q = atomAddI(&cursor_s[s], 1);
    perm_s[q] = p;
}

// ---------- dsum[n] = x[n] + sum_{e: dst=n} x[src_e]  (CSR, no atomics) ----------
__global__ void k_dsum_csr(const float* __restrict__ x, const int* __restrict__ off,
                           const int* __restrict__ srcs, float* __restrict__ dsum) {
    int team = (blockIdx.x * 256 + threadIdx.x) >> 6;   // 12500 blocks x 4 = NN
    int c = threadIdx.x & 63;
    float a0 = x[(size_t)team * 64 + c], a1 = 0.f, a2 = 0.f, a3 = 0.f;
    int e = off[team], e1 = off[team + 1];
    for (; e + 3 < e1; e += 4) {
        a0 += x[(size_t)srcs[e] * 64 + c];
        a1 += x[(size_t)srcs[e + 1] * 64 + c];
        a2 += x[(size_t)srcs[e + 2] * 64 + c];
        a3 += x[(size_t)srcs[e + 3] * 64 + c];
    }
    for (; e < e1; e++) a0 += x[(size_t)srcs[e] * 64 + c];
    dsum[(size_t)team * 64 + c] = (a0 + a1) + (a2 + a3);
}

// ---------- u = x@W_top, v = dsum@W_bot, u2 = dsum@W_top ----------
__global__ void k_uv3(const float* __restrict__ x, const float* __restrict__ dsum,
                      const float* __restrict__ W, float* __restrict__ u,
                      float* __restrict__ v, float* __restrict__ u2) {
    __shared__ float lds[4][16 * 68];
    const int lane = threadIdx.x & 63;
    const int wid = threadIdx.x >> 6;
    const int m = lane & 15, quad = lane >> 4;
    const int gwave = (blockIdx.x * blockDim.x + threadIdx.x) >> 6;
    const int nwaves = (gridDim.x * blockDim.x) >> 6;
    float* wl = lds[wid];

    bf16x8 wfh[4][4], wfl[4][4];
#pragma unroll
    for (int kk = 0; kk < 4; kk++)
#pragma unroll
        for (int ct = 0; ct < 4; ct++) {
            float wv[8];
#pragma unroll
            for (int j = 0; j < 8; j++)
                wv[j] = W[(kk * 32 + quad * 8 + j) * 64 + ct * 16 + m];
            split8r(wv, wfh[kk][ct], wfl[kk][ct]);
        }
    float zb[4] = {0.f, 0.f, 0.f, 0.f};

    for (int tile = gwave; tile < NT_N; tile += nwaves) {
        const int r = (tile << 4) + m;
        bf16x8 ah[4], al[4];
        split8(x    + (size_t)r * 64 + quad * 8,      ah[0], al[0]);
        split8(x    + (size_t)r * 64 + 32 + quad * 8, ah[1], al[1]);
        split8(dsum + (size_t)r * 64 + quad * 8,      ah[2], al[2]);
        split8(dsum + (size_t)r * 64 + 32 + quad * 8, ah[3], al[3]);

        f32x4 zero = {0.f, 0.f, 0.f, 0.f};
        f32x4 aU[4], aV[4], aU2[4];
#pragma unroll
        for (int ct = 0; ct < 4; ct++) {
            aU[ct] = zero; aV[ct] = zero; aU2[ct] = zero;
#pragma unroll
            for (int kk = 0; kk < 2; kk++) {
                aU[ct]  = __builtin_amdgcn_mfma_f32_16x16x32_bf16(al[kk],   wfh[kk][ct],   aU[ct],  0, 0, 0);
                aU[ct]  = __builtin_amdgcn_mfma_f32_16x16x32_bf16(ah[kk],   wfl[kk][ct],   aU[ct],  0, 0, 0);
                aU[ct]  = __builtin_amdgcn_mfma_f32_16x16x32_bf16(ah[kk],   wfh[kk][ct],   aU[ct],  0, 0, 0);
                aV[ct]  = __builtin_amdgcn_mfma_f32_16x16x32_bf16(al[kk+2], wfh[kk+2][ct], aV[ct],  0, 0, 0);
                aV[ct]  = __builtin_amdgcn_mfma_f32_16x16x32_bf16(ah[kk+2], wfl[kk+2][ct], aV[ct],  0, 0, 0);
                aV[ct]  = __builtin_amdgcn_mfma_f32_16x16x32_bf16(ah[kk+2], wfh[kk+2][ct], aV[ct],  0, 0, 0);
                aU2[ct] = __builtin_amdgcn_mfma_f32_16x16x32_bf16(al[kk+2], wfh[kk][ct],   aU2[ct], 0, 0, 0);
                aU2[ct] = __builtin_amdgcn_mfma_f32_16x16x32_bf16(ah[kk+2], wfl[kk][ct],   aU2[ct], 0, 0, 0);
                aU2[ct] = __builtin_amdgcn_mfma_f32_16x16x32_bf16(ah[kk+2], wfh[kk][ct],   aU2[ct], 0, 0, 0);
            }
        }
        epi_tile<false, false>(wl, lane, aU,  zb, u,  tile, nullptr, nullptr);
        epi_tile<false, false>(wl, lane, aV,  zb, v,  tile, nullptr, nullptr);
        epi_tile<false, false>(wl, lane, aU2, zb, u2, tile, nullptr, nullptr);
    }
}

// ---------- analytic stage-1 stats ----------
__global__ void k_stats1a(const float* __restrict__ u, const float* __restrict__ v,
                          const float* __restrict__ u2, const int* __restrict__ od,
                          const int* __restrict__ id, double* __restrict__ stats_raw) {
    __shared__ double lsum[4][64], lsq[4][64];
    int tid = threadIdx.x, c = tid & 63, w = tid >> 6;
    double a1 = 0.0, a2 = 0.0;
    for (int n = blockIdx.x * 4 + w; n < NN; n += gridDim.x * 4) {
        double uu = u[(size_t)n * 64 + c], vv = v[(size_t)n * 64 + c];
        double uu2 = u2[(size_t)n * 64 + c];
        double wod = 1.0 + od[n], wid = 1.0 + id[n];
        a1 += wod * uu + wid * vv;
        a2 += wod * uu * uu + wid * vv * vv + 2.0 * vv * uu2;
    }
    lsum[w][c] = a1; lsq[w][c] = a2;
    __syncthreads();
    if (w == 0) {
        a1 = lsum[0][c] + lsum[1][c] + lsum[2][c] + lsum[3][c];
        a2 = lsq[0][c] + lsq[1][c] + lsq[2][c] + lsq[3][c];
        atomAddD(&stats_raw[c], a1);
        atomAddD(&stats_raw[64 + c], a2);
    }
}

__global__ void k_fin1(const double* __restrict__ raw, const float* __restrict__ b,
                       float* __restrict__ fin, double inv_cnt) {
    int c = threadIdx.x;
    double m1 = raw[c] * inv_cnt;
    double var = raw[64 + c] * inv_cnt - m1 * m1;
    if (var < 0.0) var = 0.0;
    fin[c] = (float)(m1 + (double)b[c]);
    fin[64 + c] = (float)(1.0 / sqrt(var + 1e-5));
}

__global__ void k_fin(const double* __restrict__ raw, float* __restrict__ fin, double inv_cnt) {
    int c = threadIdx.x;
    double mean = raw[c] * inv_cnt;
    double var = raw[64 + c] * inv_cnt - mean * mean;
    if (var < 0.0) var = 0.0;
    fin[c] = (float)mean;
    fin[64 + c] = (float)(1.0 / sqrt(var + 1e-5));
}

// ---------- s_tab[n] = relu(bn1(u[n]+v[n]+b)) + sum_{e:dst=n} relu(bn1(u[src]+v[n]+b)) ----------
__global__ void k_s1_csr(const float* __restrict__ u, const float* __restrict__ v,
                         const int* __restrict__ off, const int* __restrict__ srcs,
                         const float* __restrict__ b_un, const float* __restrict__ fin,
                         const float* __restrict__ g1, const float* __restrict__ be1,
                         float* __restrict__ s_tab) {
    int team = (blockIdx.x * 256 + threadIdx.x) >> 6;
    int c = threadIdx.x & 63;
    float sc = fin[64 + c] * g1[c];
    float tsh = (b_un[c] - fin[c]) * sc + be1[c];
    float vn = v[(size_t)team * 64 + c];
    float a0 = fmaxf((u[(size_t)team * 64 + c] + vn) * sc + tsh, 0.f);   // self row
    float a1 = 0.f, a2 = 0.f, a3 = 0.f;
    int e = off[team], e1 = off[team + 1];
    for (; e + 3 < e1; e += 4) {
        a0 += fmaxf((u[(size_t)srcs[e] * 64 + c] + vn) * sc + tsh, 0.f);
        a1 += fmaxf((u[(size_t)srcs[e + 1] * 64 + c] + vn) * sc + tsh, 0.f);
        a2 += fmaxf((u[(size_t)srcs[e + 2] * 64 + c] + vn) * sc + tsh, 0.f);
        a3 += fmaxf((u[(size_t)srcs[e + 3] * 64 + c] + vn) * sc + tsh, 0.f);
    }
    for (; e < e1; e++) a0 += fmaxf((u[(size_t)srcs[e] * 64 + c] + vn) * sc + tsh, 0.f);
    s_tab[(size_t)team * 64 + c] = (a0 + a1) + (a2 + a3);
}

// ---------- msg[n] = sum_{e:dst=n} s_tab[src_e] ----------
__global__ void k_msg_csr(const int* __restrict__ off, const int* __restrict__ srcs,
                          const float* __restrict__ s_tab, float* __restrict__ msg) {
    int team = (blockIdx.x * 256 + threadIdx.x) >> 6;
    int c = threadIdx.x & 63;
    float a0 = 0.f, a1 = 0.f, a2 = 0.f, a3 = 0.f;
    int e = off[team], e1 = off[team + 1];
    for (; e + 3 < e1; e += 4) {
        a0 += s_tab[(size_t)srcs[e] * 64 + c];
        a1 += s_tab[(size_t)srcs[e + 1] * 64 + c];
        a2 += s_tab[(size_t)srcs[e + 2] * 64 + c];
        a3 += s_tab[(size_t)srcs[e + 3] * 64 + c];
    }
    for (; e < e1; e++) a0 += s_tab[(size_t)srcs[e] * 64 + c];
    msg[(size_t)team * 64 + c] = (a0 + a1) + (a2 + a3);
}

// ---------- mb = msg @ W_gc[64:128]  (streaming, IN PLACE over msg) ----------
__global__ void k_mb(float* msg, const float* __restrict__ W) {
    __shared__ float lds[4][16 * 68];
    const int lane = threadIdx.x & 63;
    const int wid = threadIdx.x >> 6;
    const int m = lane & 15, quad = lane >> 4;
    const int gwave = (blockIdx.x * blockDim.x + threadIdx.x) >> 6;
    const int nwaves = (gridDim.x * blockDim.x) >> 6;
    float* wl = lds[wid];

    bf16x8 wfh[2][4], wfl[2][4];
#pragma unroll
    for (int kk = 0; kk < 2; kk++)
#pragma unroll
        for (int ct = 0; ct < 4; ct++) {
            float wv[8];
#pragma unroll
            for (int j = 0; j < 8; j++)
                wv[j] = W[(kk * 32 + quad * 8 + j) * 64 + ct * 16 + m];
            split8r(wv, wfh[kk][ct], wfl[kk][ct]);
        }
    float zb[4] = {0.f, 0.f, 0.f, 0.f};

    for (int tile = gwave; tile < NT_N; tile += nwaves) {
        const int r = (tile << 4) + m;
        bf16x8 ah[2], al[2];
        split8(msg + (size_t)r * 64 + quad * 8,      ah[0], al[0]);
        split8(msg + (size_t)r * 64 + 32 + quad * 8, ah[1], al[1]);

        f32x4 zero = {0.f, 0.f, 0.f, 0.f};
        f32x4 acc[4];
#pragma unroll
        for (int ct = 0; ct < 4; ct++) {
            acc[ct] = zero;
#pragma unroll
            for (int kk = 0; kk < 2; kk++) {
                acc[ct] = __builtin_amdgcn_mfma_f32_16x16x32_bf16(al[kk], wfh[kk][ct], acc[ct], 0, 0, 0);
                acc[ct] = __builtin_amdgcn_mfma_f32_16x16x32_bf16(ah[kk], wfl[kk][ct], acc[ct], 0, 0, 0);
                acc[ct] = __builtin_amdgcn_mfma_f32_16x16x32_bf16(ah[kk], wfh[kk][ct], acc[ct], 0, 0, 0);
            }
        }
        epi_tile<false, false>(wl, lane, acc, zb, msg, tile, nullptr, nullptr);
    }
}

// ---------- stage-2: h2_pre[row] = relu(bn1(u[sr]+v[dm]+b_un)) @ Wtop2 + mb[dm] + b_gc
// K=64. Edge rows dst-sorted (v/mb gathers near-uniform per tile); stats in f64.
__global__ void k_ph0(const float* __restrict__ u, const float* __restrict__ v,
                      const float* __restrict__ mb, const int* __restrict__ srcs_s,
                      const int* __restrict__ dsts_s,
                      const float* __restrict__ W, const float* __restrict__ b_un,
                      const float* __restrict__ b_gc,
                      const float* __restrict__ fin1, const float* __restrict__ g1,
                      const float* __restrict__ be1,
                      float* __restrict__ h2pre, double* __restrict__ stats_raw) {
    __shared__ float lds[4][16 * 68];
    const int lane = threadIdx.x & 63;
    const int wid = threadIdx.x >> 6;
    const int m = lane & 15, quad = lane >> 4;
    const int gwave = (blockIdx.x * blockDim.x + threadIdx.x) >> 6;
    const int nwaves = (gridDim.x * blockDim.x) >> 6;
    float* wl = lds[wid];

    bf16x8 wfh[2][4], wfl[2][4];
#pragma unroll
    for (int kk = 0; kk < 2; kk++)
#pragma unroll
        for (int ct = 0; ct < 4; ct++) {
            float wv[8];
#pragma unroll
            for (int j = 0; j < 8; j++)
                wv[j] = W[(kk * 32 + quad * 8 + j) * 64 + ct * 16 + m];
            split8r(wv, wfh[kk][ct], wfl[kk][ct]);
        }

    float bv[4];
#pragma unroll
    for (int ct = 0; ct < 4; ct++) bv[ct] = b_gc[ct * 16 + m];

    float s1f[2][8], t1f[2][8];
#pragma unroll
    for (int kk = 0; kk < 2; kk++)
#pragma unroll
        for (int j = 0; j < 8; j++) {
            int c = kk * 32 + quad * 8 + j;
            float sc = fin1[64 + c] * g1[c];
            s1f[kk][j] = sc;
            t1f[kk][j] = be1[c] + (b_un[c] - fin1[c]) * sc;
        }

    double ssum[4] = {0,0,0,0}, ssq[4] = {0,0,0,0};

    for (int tile = gwave; tile < NT_R; tile += nwaves) {
        const int r = (tile << 4) + m;
        const bool selftile = (tile < NT_N);
        int sr = selftile ? r : srcs_s[r - NN];
        int dm = selftile ? r : dsts_s[r - NN];

        bf16x8 ah[2], al[2];
#pragma unroll
        for (int kk = 0; kk < 2; kk++) {
            f32x4 u0 = *reinterpret_cast<const f32x4*>(u + (size_t)sr * 64 + kk * 32 + quad * 8);
            f32x4 u1 = *reinterpret_cast<const f32x4*>(u + (size_t)sr * 64 + kk * 32 + quad * 8 + 4);
            f32x4 v0 = *reinterpret_cast<const f32x4*>(v + (size_t)dm * 64 + kk * 32 + quad * 8);
            f32x4 v1 = *reinterpret_cast<const f32x4*>(v + (size_t)dm * 64 + kk * 32 + quad * 8 + 4);
            float tv[8];
#pragma unroll
            for (int j = 0; j < 4; j++) {
                tv[j]     = fmaxf((u0[j] + v0[j]) * s1f[kk][j]     + t1f[kk][j],     0.f);
                tv[4 + j] = fmaxf((u1[j] + v1[j]) * s1f[kk][4 + j] + t1f[kk][4 + j], 0.f);
            }
            split8r(tv, ah[kk], al[kk]);
        }

        f32x4 zero = {0.f, 0.f, 0.f, 0.f};
        f32x4 acc[4];
#pragma unroll
        for (int ct = 0; ct < 4; ct++) {
            acc[ct] = zero;
#pragma unroll
            for (int kk = 0; kk < 2; kk++) {
                acc[ct] = __builtin_amdgcn_mfma_f32_16x16x32_bf16(al[kk], wfh[kk][ct], acc[ct], 0, 0, 0);
                acc[ct] = __builtin_amdgcn_mfma_f32_16x16x32_bf16(ah[kk], wfl[kk][ct], acc[ct], 0, 0, 0);
                acc[ct] = __builtin_amdgcn_mfma_f32_16x16x32_bf16(ah[kk], wfh[kk][ct], acc[ct], 0, 0, 0);
            }
        }

        // add mb[dm_of_row] + b_gc per element, then stats + LDS-coalesced store
#pragma unroll
        for (int i = 0; i < 4; i++) {
            int dmv = __shfl(dm, (lane & 48) + quad * 4 + i, 64);   // dm of row quad*4+i
#pragma unroll
            for (int ct = 0; ct < 4; ct++) {
                float val = acc[ct][i] + bv[ct] + mb[(size_t)dmv * 64 + ct * 16 + m];
                wl[(quad * 4 + i) * 68 + ct * 16 + m] = val;
                ssum[ct] += (double)val;
                ssq[ct]  += (double)val * (double)val;
            }
        }
        asm volatile("s_waitcnt lgkmcnt(0)" ::: "memory");
#pragma unroll
        for (int j = 0; j < 4; j++) {
            int row = j * 4 + quad;
            f32x4 vv = *reinterpret_cast<const f32x4*>(wl + row * 68 + m * 4);
            *reinterpret_cast<f32x4*>(h2pre + ((size_t)(tile << 4) + row) * 64 + m * 4) = vv;
        }
    }

#pragma unroll
    for (int ct = 0; ct < 4; ct++) {
        double sv = ssum[ct], qv = ssq[ct];
        sv += __shfl_xor(sv, 16, 64); sv += __shfl_xor(sv, 32, 64);
        qv += __shfl_xor(qv, 16, 64); qv += __shfl_xor(qv, 32, 64);
        if (quad == 0) {
            atomAddD(&stats_raw[ct * 16 + m], sv);
            atomAddD(&stats_raw[64 + ct * 16 + m], qv);
        }
    }
}

// ---------- agg[n] = relu(bn2(h2pre[n])) + sum_{q in src-CSR} relu(bn2(h2pre[NN+perm_s[q]]))
// No atomics: sequential per-node reduction, random full-row reads (each row read once).
__global__ void k_agg_csr(const float* __restrict__ h2pre, const int* __restrict__ off_s,
                          const int* __restrict__ perm_s, const float* __restrict__ fin2,
                          const float* __restrict__ g2, const float* __restrict__ be2,
                          float* __restrict__ agg) {
    int n = (blockIdx.x * 256 + threadIdx.x) >> 6;
    int c = threadIdx.x & 63;
    float sc = fin2[64 + c] * g2[c];
    float sh = be2[c] - fin2[c] * sc;
    float a0 = fmaxf(h2pre[(size_t)n * 64 + c] * sc + sh, 0.f);   // self row
    float a1 = 0.f, a2 = 0.f, a3 = 0.f;
    int q = off_s[n], q1 = off_s[n + 1];
    for (; q + 3 < q1; q += 4) {
        a0 += fmaxf(h2pre[(size_t)(NN + perm_s[q])     * 64 + c] * sc + sh, 0.f);
        a1 += fmaxf(h2pre[(size_t)(NN + perm_s[q + 1]) * 64 + c] * sc + sh, 0.f);
        a2 += fmaxf(h2pre[(size_t)(NN + perm_s[q + 2]) * 64 + c] * sc + sh, 0.f);
        a3 += fmaxf(h2pre[(size_t)(NN + perm_s[q + 3]) * 64 + c] * sc + sh, 0.f);
    }
    for (; q < q1; q++) a0 += fmaxf(h2pre[(size_t)(NN + perm_s[q]) * 64 + c] * sc + sh, 0.f);
    agg[(size_t)n * 64 + c] = (a0 + a1) + (a2 + a3);
}

// ---------- stage 3: t_pre = [relu(bn2(h2pre[:N])), agg] @ W_tr + b_tr, stats3 ----------
__global__ void k_mm3(const float* __restrict__ h2pre, const float* __restrict__ agg,
                      const float* __restrict__ W, const float* __restrict__ bias,
                      const float* __restrict__ fin2, const float* __restrict__ g2,
                      const float* __restrict__ be2,
                      float* __restrict__ outp, double* __restrict__ stats_raw) {
    __shared__ float lds[4][16 * 68];
    const int lane = threadIdx.x & 63;
    const int wid = threadIdx.x >> 6;
    const int m = lane & 15, quad = lane >> 4;
    const int gwave = (blockIdx.x * blockDim.x + threadIdx.x) >> 6;
    const int nwaves = (gridDim.x * blockDim.x) >> 6;
    float* wl = lds[wid];

    bf16x8 wfh[4][4], wfl[4][4];
#pragma unroll
    for (int kk = 0; kk < 4; kk++)
#pragma unroll
        for (int ct = 0; ct < 4; ct++) {
            float wv[8];
#pragma unroll
            for (int j = 0; j < 8; j++)
                wv[j] = W[(kk * 32 + quad * 8 + j) * 64 + ct * 16 + m];
            split8r(wv, wfh[kk][ct], wfl[kk][ct]);
        }

    float bv[4];
#pragma unroll
    for (int ct = 0; ct < 4; ct++) bv[ct] = bias[ct * 16 + m];

    float s2f[2][8], t2f[2][8];
#pragma unroll
    for (int kk = 0; kk < 2; kk++)
#pragma unroll
        for (int j = 0; j < 8; j++) {
            int c = kk * 32 + quad * 8 + j;
            float sc = fin2[64 + c] * g2[c];
            s2f[kk][j] = sc;
            t2f[kk][j] = be2[c] - fin2[c] * sc;
        }

    double ssum[4] = {0,0,0,0}, ssq[4] = {0,0,0,0};

    for (int tile = gwave; tile < NT_N; tile += nwaves) {
        const int r = (tile << 4) + m;
        bf16x8 ah[4], al[4];
#pragma unroll
        for (int kk = 0; kk < 2; kk++) {
            f32x4 v0 = *reinterpret_cast<const f32x4*>(h2pre + (size_t)r * 64 + kk * 32 + quad * 8);
            f32x4 v1 = *reinterpret_cast<const f32x4*>(h2pre + (size_t)r * 64 + kk * 32 + quad * 8 + 4);
            float tv[8];
#pragma unroll
            for (int j = 0; j < 4; j++) {
                tv[j]     = fmaxf(v0[j] * s2f[kk][j]     + t2f[kk][j],     0.f);
                tv[4 + j] = fmaxf(v1[j] * s2f[kk][4 + j] + t2f[kk][4 + j], 0.f);
            }
            split8r(tv, ah[kk], al[kk]);
        }
        split8(agg + (size_t)r * 64 + quad * 8,      ah[2], al[2]);
        split8(agg + (size_t)r * 64 + 32 + quad * 8, ah[3], al[3]);

        f32x4 zero = {0.f, 0.f, 0.f, 0.f};
        f32x4 acc[4];
#pragma unroll
        for (int ct = 0; ct < 4; ct++) {
            acc[ct] = zero;
#pragma unroll
            for (int kk = 0; kk < 4; kk++)
                acc[ct] = __builtin_amdgcn_mfma_f32_16x16x32_bf16(al[kk], wfh[kk][ct], acc[ct], 0, 0, 0);
#pragma unroll
            for (int kk = 0; kk < 4; kk++)
                acc[ct] = __builtin_amdgcn_mfma_f32_16x16x32_bf16(ah[kk], wfl[kk][ct], acc[ct], 0, 0, 0);
#pragma unroll
            for (int kk = 0; kk < 4; kk++)
                acc[ct] = __builtin_amdgcn_mfma_f32_16x16x32_bf16(ah[kk], wfh[kk][ct], acc[ct], 0, 0, 0);
        }

        epi_tile<false, true>(wl, lane, acc, bv, outp, tile, ssum, ssq);
    }

#pragma unroll
    for (int ct = 0; ct < 4; ct++) {
        double sv = ssum[ct], qv = ssq[ct];
        sv += __shfl_xor(sv, 16, 64); sv += __shfl_xor(sv, 32, 64);
        qv += __shfl_xor(qv, 16, 64); qv += __shfl_xor(qv, 32, 64);
        if (quad == 0) {
            atomAddD(&stats_raw[ct * 16 + m], sv);
            atomAddD(&stats_raw[64 + ct * 16 + m], qv);
        }
    }
}

// ---------- stage 4 ----------
__global__ void k_mm4(const float* __restrict__ tpre, const float* __restrict__ W,
                      const float* __restrict__ bias, const float* __restrict__ fin3,
                      const float* __restrict__ g2, const float* __restrict__ be2,
                      float* __restrict__ outp, double* __restrict__ stats_raw) {
    __shared__ float lds[4][16 * 68];
    const int lane = threadIdx.x & 63;
    const int wid = threadIdx.x >> 6;
    const int m = lane & 15, quad = lane >> 4;
    const int gwave = (blockIdx.x * blockDim.x + threadIdx.x) >> 6;
    const int nwaves = (gridDim.x * blockDim.x) >> 6;
    float* wl = lds[wid];

    bf16x8 wfh[2][4], wfl[2][4];
#pragma unroll
    for (int kk = 0; kk < 2; kk++)
#pragma unroll
        for (int ct = 0; ct < 4; ct++) {
            float wv[8];
#pragma unroll
            for (int j = 0; j < 8; j++)
                wv[j] = W[(kk * 32 + quad * 8 + j) * 64 + ct * 16 + m];
            split8r(wv, wfh[kk][ct], wfl[kk][ct]);
        }

    float bv[4];
#pragma unroll
    for (int ct = 0; ct < 4; ct++) bv[ct] = bias[ct * 16 + m];

    float sc[2][8], sh[2][8];
#pragma unroll
    for (int kk = 0; kk < 2; kk++)
#pragma unroll
        for (int j = 0; j < 8; j++) {
            int c = kk * 32 + quad * 8 + j;
            float s = fin3[64 + c] * g2[c];
            sc[kk][j] = s;
            sh[kk][j] = be2[c] - fin3[c] * s;
        }

    double ssum[4] = {0,0,0,0}, ssq[4] = {0,0,0,0};

    for (int tile = gwave; tile < NT_N; tile += nwaves) {
        const int r = (tile << 4) + m;
        bf16x8 ah[2], al[2];
#pragma unroll
        for (int kk = 0; kk < 2; kk++) {
            f32x4 v0 = *reinterpret_cast<const f32x4*>(tpre + (size_t)r * 64 + kk * 32 + quad * 8);
            f32x4 v1 = *reinterpret_cast<const f32x4*>(tpre + (size_t)r * 64 + kk * 32 + quad * 8 + 4);
            float tv[8];
#pragma unroll
            for (int j = 0; j < 4; j++) {
                tv[j]     = fmaxf(v0[j] * sc[kk][j]     + sh[kk][j],     0.f);
                tv[4 + j] = fmaxf(v1[j] * sc[kk][4 + j] + sh[kk][4 + j], 0.f);
            }
            split8r(tv, ah[kk], al[kk]);
        }

        f32x4 zero = {0.f, 0.f, 0.f, 0.f};
        f32x4 acc[4];
#pragma unroll
        for (int ct = 0; ct < 4; ct++) {
            acc[ct] = zero;
#pragma unroll
            for (int kk = 0; kk < 2; kk++) {
                acc[ct] = __builtin_amdgcn_mfma_f32_16x16x32_bf16(al[kk], wfh[kk][ct], acc[ct], 0, 0, 0);
                acc[ct] = __builtin_amdgcn_mfma_f32_16x16x32_bf16(ah[kk], wfl[kk][ct], acc[ct], 0, 0, 0);
                acc[ct] = __builtin_amdgcn_mfma_f32_16x16x32_bf16(ah[kk], wfh[kk][ct], acc[ct], 0, 0, 0);
            }
        }

        epi_tile<true, true>(wl, lane, acc, bv, outp, tile, ssum, ssq);
    }

#pragma unroll
    for (int ct = 0; ct < 4; ct++) {
        double sv = ssum[ct], qv = ssq[ct];
        sv += __shfl_xor(sv, 16, 64); sv += __shfl_xor(sv, 32, 64);
        qv += __shfl_xor(qv, 16, 64); qv += __shfl_xor(qv, 32, 64);
        if (quad == 0) {
            atomAddD(&stats_raw[ct * 16 + m], sv);
            atomAddD(&stats_raw[64 + ct * 16 + m], qv);
        }
    }
}

// out = relu(bn(out_pre; stats4, g3, be3)) -> f32
__global__ void k_out(const float* __restrict__ op, const float* __restrict__ fin,
                      const float* __restrict__ g, const float* __restrict__ be,
                      float* __restrict__ out) {
    int i = blockIdx.x * 256 + threadIdx.x;   // covers NN*64 exactly
    int c = i & 63;
    out[i] = fmaxf((op[i] - fin[c]) * fin[64 + c] * g[c] + be[c], 0.f);
}

extern "C" void kernel_launch(void* const* d_in, const int* in_sizes, int n_in,
                              void* d_out, int out_size, void* d_ws, size_t ws_size,
                              hipStream_t stream) {
    const float* x    = (const float*)d_in[0];
    const int*   ei   = (const int*)d_in[1];
    const float* W_un = (const float*)d_in[2];
    const float* b_un = (const float*)d_in[3];
    const float* g1   = (const float*)d_in[4];
    const float* be1  = (const float*)d_in[5];
    const float* W_gc = (const float*)d_in[6];
    const float* b_gc = (const float*)d_in[7];
    const float* g2   = (const float*)d_in[8];
    const float* be2  = (const float*)d_in[9];
    const float* W_tr = (const float*)d_in[10];
    const float* b_tr = (const float*)d_in[11];
    const float* W_li = (const float*)d_in[12];
    const float* b_li = (const float*)d_in[13];
    const float* g3   = (const float*)d_in[14];
    const float* be3  = (const float*)d_in[15];

    float* ws = (float*)d_ws;
    const size_t FN = (size_t)NN * 64;           // 3.2M floats (12.8 MB)
    const size_t FR = (size_t)RR * 64;           // 54.4M floats (217.6 MB)
    // Slots:  P0: u -> agg    P1: v -> tpre    P2: msg -> mb (in place) -> outpre
    //         H : [s_tab | dsum | u2] early -> h2pre (R rows)
    //         tail: stats_raw | od | id | off | cursor | off_s | cursor_s |
    //               srcs_s | dsts_s | perm_s | stats_fin   (~10.9 MB)
    float*  P0 = ws;
    float*  P1 = ws + FN;
    float*  P2 = ws + 2 * FN;
    float*  H  = ws + 3 * FN;
    float*  u      = P0;
    float*  v      = P1;
    float*  msg    = P2;          // becomes mb after k_mb (in place)
    float*  s_tab  = H;
    float*  dsum   = H + FN;
    float*  u2     = H + 2 * FN;
    float*  h2pre  = H;
    float*  agg    = P0;
    float*  tpre   = P1;
    float*  outpre = P2;
    double* stats_raw = (double*)(H + FR);
    int*    od        = (int*)(stats_raw + 512);
    int*    id        = od + NN;
    int*    off       = id + NN;
    int*    cursor    = off + NN + 1;
    int*    off_s     = cursor + NN;
    int*    cursor_s  = off_s + NN + 1;
    int*    srcs_s    = cursor_s + NN;
    int*    dsts_s    = srcs_s + EE;
    int*    perm_s    = dsts_s + EE;
    float*  stats_fin = (float*)(perm_s + EE);

    // zero: stats_raw + od + id (contiguous)
    hipMemsetAsync(stats_raw, 0, 512 * sizeof(double) + 2 * NN * sizeof(int), stream);

    // build dst-sorted edge list + src-CSR permutation
    k_deg  <<<3125, 256,  0, stream>>>(ei, od, id);
    k_scan <<<1,    1024, 0, stream>>>(id, off, cursor);      // dst-CSR
    k_scan <<<1,    1024, 0, stream>>>(od, off_s, cursor_s);  // src-CSR
    k_fill <<<3125, 256,  0, stream>>>(ei, cursor, srcs_s, dsts_s);
    k_fill2<<<3125, 256,  0, stream>>>(srcs_s, cursor_s, perm_s);

    // stage 0 + per-node tables
    k_dsum_csr<<<12500, 256, 0, stream>>>(x, off, srcs_s, dsum);
    k_uv3<<<512, 256, 0, stream>>>(x, dsum, W_un, u, v, u2);

    // stage-1: analytic stats, then CSR reductions
    k_stats1a<<<256, 256, 0, stream>>>(u, v, u2, od, id, stats_raw + 0);
    k_fin1<<<1, 64, 0, stream>>>(stats_raw + 0, b_un, stats_fin + 0, 1.0 / (double)RR);
    k_s1_csr<<<12500, 256, 0, stream>>>(u, v, off, srcs_s, b_un, stats_fin + 0, g1, be1, s_tab);
    k_msg_csr<<<12500, 256, 0, stream>>>(off, srcs_s, s_tab, msg);
    k_mb<<<512, 256, 0, stream>>>(msg, W_gc + 64 * 64);       // msg -> mb in place

    // stage-2: one gather pass (K=64, stats + h2pre), then src-CSR aggregate (no atomics)
    k_ph0<<<2048, 256, 0, stream>>>(u, v, msg, srcs_s, dsts_s, W_gc, b_un, b_gc,
                                    stats_fin + 0, g1, be1, h2pre, stats_raw + 128);
    k_fin<<<1, 64, 0, stream>>>(stats_raw + 128, stats_fin + 128, 1.0 / (double)RR);
    k_agg_csr<<<12500, 256, 0, stream>>>(h2pre, off_s, perm_s, stats_fin + 128, g2, be2, agg);

    // stage 3
    k_mm3<<<512, 256, 0, stream>>>(h2pre, agg, W_tr, b_tr, stats_fin + 128, g2, be2,
                                   tpre, stats_raw + 256);
    k_fin<<<1, 64, 0, stream>>>(stats_raw + 256, stats_fin + 256, 1.0 / (double)NN);

    // stage 4
    k_mm4<<<512, 256, 0, stream>>>(tpre, W_li, b_li, stats_fin + 256, g2, be2,
                                   outpre, stats_raw + 384);
    k_fin<<<1, 64, 0, stream>>>(stats_raw + 384, stats_fin + 384, 1.0 / (double)NN);

    k_out<<<12500, 256, 0, stream>>>(outpre, stats_fin + 384, g3, be3, (float*)d_out);
}

// Round 11
// 1209.964 us; speedup vs baseline: 1.7782x; 1.0276x over previous
//
#include <hip/hip_runtime.h>
#include <cstdint>
#include <math.h>

// Problem sizes (fixed by the reference).
#define NN 50000
#define EE 800000
#define RR 850000      // NN + EE rows
#define NT_N 3125      // NN/16
#define NT_R 53125     // RR/16

typedef short  bf16x8 __attribute__((ext_vector_type(8)));
typedef float  f32x4  __attribute__((ext_vector_type(4)));

__device__ __forceinline__ float bf2f(unsigned short b) {
    unsigned int u = ((unsigned int)b) << 16;
    return __builtin_bit_cast(float, u);
}
__device__ __forceinline__ unsigned short f2bf(float f) {
    unsigned int u = __builtin_bit_cast(unsigned int, f);
    u = u + 0x7fffu + ((u >> 16) & 1u);
    return (unsigned short)(u >> 16);
}
__device__ __forceinline__ void atomAddF(float* p, float v) { unsafeAtomicAdd(p, v); }
__device__ __forceinline__ void atomAddD(double* p, double v) { unsafeAtomicAdd(p, v); }
__device__ __forceinline__ int atomAddI(int* p, int v) { return atomicAdd(p, v); }

// split 8 consecutive f32 into hi/lo bf16 fragments: hi+lo == v to ~2^-16 rel
__device__ __forceinline__ void split8(const float* p, bf16x8& hi, bf16x8& lo) {
    f32x4 v0 = *reinterpret_cast<const f32x4*>(p);
    f32x4 v1 = *reinterpret_cast<const f32x4*>(p + 4);
#pragma unroll
    for (int j = 0; j < 4; j++) {
        unsigned short h0 = f2bf(v0[j]);
        hi[j] = (short)h0; lo[j] = (short)f2bf(v0[j] - bf2f(h0));
        unsigned short h1 = f2bf(v1[j]);
        hi[4 + j] = (short)h1; lo[4 + j] = (short)f2bf(v1[j] - bf2f(h1));
    }
}
__device__ __forceinline__ void split8r(const float* v, bf16x8& hi, bf16x8& lo) {
#pragma unroll
    for (int j = 0; j < 8; j++) {
        unsigned short h = f2bf(v[j]);
        hi[j] = (short)h; lo[j] = (short)f2bf(v[j] - bf2f(h));
    }
}

// LDS-staged coalesced tile store: MFMA C-layout -> 4x 1KB contiguous dwordx4 stores.
template <bool RELU, bool STATS>
__device__ __forceinline__ void epi_tile(float* wl, int lane, const f32x4* acc,
                                         const float* bv, float* __restrict__ gout,
                                         int tile, double* ssum, double* ssq) {
    const int m = lane & 15, quad = lane >> 4;
#pragma unroll
    for (int ct = 0; ct < 4; ct++)
#pragma unroll
        for (int i = 0; i < 4; i++) {
            float val = acc[ct][i] + bv[ct];
            if (RELU) val = fmaxf(val, 0.f);
            wl[(quad * 4 + i) * 68 + ct * 16 + m] = val;
            if (STATS) { ssum[ct] += (double)val; ssq[ct] += (double)val * (double)val; }
        }
    asm volatile("s_waitcnt lgkmcnt(0)" ::: "memory");
#pragma unroll
    for (int j = 0; j < 4; j++) {
        int row = j * 4 + quad;
        f32x4 vv = *reinterpret_cast<const f32x4*>(wl + row * 68 + m * 4);
        *reinterpret_cast<f32x4*>(gout + ((size_t)(tile << 4) + row) * 64 + m * 4) = vv;
    }
}

// ---------- degree counts ----------
__global__ void k_deg(const int* __restrict__ ei, int* __restrict__ od, int* __restrict__ id) {
    int e = blockIdx.x * 256 + threadIdx.x;   // covers EE exactly
    atomAddI(&od[ei[e]], 1);
    atomAddI(&id[ei[EE + e]], 1);
}

// ---------- exclusive scan of counts -> off, cursor (single block; generic) ----------
__global__ void __launch_bounds__(1024) k_scan(const int* __restrict__ cnt,
                                               int* __restrict__ off, int* __restrict__ cursor) {
    __shared__ int part[1024];
    const int t = threadIdx.x;
    const int CH = (NN + 1023) / 1024;   // 49
    int base = t * CH, s = 0;
    for (int i = 0; i < CH; i++) { int idx = base + i; if (idx < NN) s += cnt[idx]; }
    part[t] = s;
    __syncthreads();
    if (t == 0) {
        int run = 0;
        for (int i = 0; i < 1024; i++) { int x = part[i]; part[i] = run; run += x; }
    }
    __syncthreads();
    int run = part[t];
    for (int i = 0; i < CH; i++) {
        int idx = base + i;
        if (idx < NN) { off[idx] = run; cursor[idx] = run; run += cnt[idx]; }
    }
    if (t == 0) off[NN] = EE;
}

// ---------- fill dst-sorted edge arrays ----------
__global__ void k_fill(const int* __restrict__ ei, int* __restrict__ cursor,
                       int* __restrict__ srcs_s, int* __restrict__ dsts_s) {
    int e = blockIdx.x * 256 + threadIdx.x;   // covers EE exactly
    int d = ei[EE + e];
    int p = atomAddI(&cursor[d], 1);          // old value = fill position
    srcs_s[p] = ei[e];
    dsts_s[p] = d;
}

// ---------- fill src-CSR permutation: perm_s[q] = dst-order position p ----------
__global__ void k_fill2(const int* __restrict__ srcs_s, int* __restrict__ cursor_s,
                        int* __restrict__ perm_s) {
    int p = blockIdx.x * 256 + threadIdx.x;   // covers EE exactly
    int s = srcs_s[p];
    int q = atomAddI(&cursor_s[s], 1);
    perm_s[q] = p;
}

// ---------- dsum[n] = x[n] + sum_{e: dst=n} x[src_e]  (CSR, no atomics, 8-way MLP) ----------
__global__ void k_dsum_csr(const float* __restrict__ x, const int* __restrict__ off,
                           const int* __restrict__ srcs, float* __restrict__ dsum) {
    int team = (blockIdx.x * 256 + threadIdx.x) >> 6;   // 12500 blocks x 4 = NN
    int c = threadIdx.x & 63;
    float a[8] = {x[(size_t)team * 64 + c], 0.f, 0.f, 0.f, 0.f, 0.f, 0.f, 0.f};
    int e = off[team], e1 = off[team + 1];
    for (; e + 7 < e1; e += 8)
#pragma unroll
        for (int j = 0; j < 8; j++) a[j] += x[(size_t)srcs[e + j] * 64 + c];
    for (; e < e1; e++) a[0] += x[(size_t)srcs[e] * 64 + c];
    dsum[(size_t)team * 64 + c] = ((a[0] + a[1]) + (a[2] + a[3])) + ((a[4] + a[5]) + (a[6] + a[7]));
}

// ---------- u = x@W_top, v = dsum@W_bot, u2 = dsum@W_top ----------
__global__ void k_uv3(const float* __restrict__ x, const float* __restrict__ dsum,
                      const float* __restrict__ W, float* __restrict__ u,
                      float* __restrict__ v, float* __restrict__ u2) {
    __shared__ float lds[4][16 * 68];
    const int lane = threadIdx.x & 63;
    const int wid = threadIdx.x >> 6;
    const int m = lane & 15, quad = lane >> 4;
    const int gwave = (blockIdx.x * blockDim.x + threadIdx.x) >> 6;
    const int nwaves = (gridDim.x * blockDim.x) >> 6;
    float* wl = lds[wid];

    bf16x8 wfh[4][4], wfl[4][4];
#pragma unroll
    for (int kk = 0; kk < 4; kk++)
#pragma unroll
        for (int ct = 0; ct < 4; ct++) {
            float wv[8];
#pragma unroll
            for (int j = 0; j < 8; j++)
                wv[j] = W[(kk * 32 + quad * 8 + j) * 64 + ct * 16 + m];
            split8r(wv, wfh[kk][ct], wfl[kk][ct]);
        }
    float zb[4] = {0.f, 0.f, 0.f, 0.f};

    for (int tile = gwave; tile < NT_N; tile += nwaves) {
        const int r = (tile << 4) + m;
        bf16x8 ah[4], al[4];
        split8(x    + (size_t)r * 64 + quad * 8,      ah[0], al[0]);
        split8(x    + (size_t)r * 64 + 32 + quad * 8, ah[1], al[1]);
        split8(dsum + (size_t)r * 64 + quad * 8,      ah[2], al[2]);
        split8(dsum + (size_t)r * 64 + 32 + quad * 8, ah[3], al[3]);

        f32x4 zero = {0.f, 0.f, 0.f, 0.f};
        f32x4 aU[4], aV[4], aU2[4];
#pragma unroll
        for (int ct = 0; ct < 4; ct++) {
            aU[ct] = zero; aV[ct] = zero; aU2[ct] = zero;
#pragma unroll
            for (int kk = 0; kk < 2; kk++) {
                aU[ct]  = __builtin_amdgcn_mfma_f32_16x16x32_bf16(al[kk],   wfh[kk][ct],   aU[ct],  0, 0, 0);
                aU[ct]  = __builtin_amdgcn_mfma_f32_16x16x32_bf16(ah[kk],   wfl[kk][ct],   aU[ct],  0, 0, 0);
                aU[ct]  = __builtin_amdgcn_mfma_f32_16x16x32_bf16(ah[kk],   wfh[kk][ct],   aU[ct],  0, 0, 0);
                aV[ct]  = __builtin_amdgcn_mfma_f32_16x16x32_bf16(al[kk+2], wfh[kk+2][ct], aV[ct],  0, 0, 0);
                aV[ct]  = __builtin_amdgcn_mfma_f32_16x16x32_bf16(ah[kk+2], wfl[kk+2][ct], aV[ct],  0, 0, 0);
                aV[ct]  = __builtin_amdgcn_mfma_f32_16x16x32_bf16(ah[kk+2], wfh[kk+2][ct], aV[ct],  0, 0, 0);
                aU2[ct] = __builtin_amdgcn_mfma_f32_16x16x32_bf16(al[kk+2], wfh[kk][ct],   aU2[ct], 0, 0, 0);
                aU2[ct] = __builtin_amdgcn_mfma_f32_16x16x32_bf16(ah[kk+2], wfl[kk][ct],   aU2[ct], 0, 0, 0);
                aU2[ct] = __builtin_amdgcn_mfma_f32_16x16x32_bf16(ah[kk+2], wfh[kk][ct],   aU2[ct], 0, 0, 0);
            }
        }
        epi_tile<false, false>(wl, lane, aU,  zb, u,  tile, nullptr, nullptr);
        epi_tile<false, false>(wl, lane, aV,  zb, v,  tile, nullptr, nullptr);
        epi_tile<false, false>(wl, lane, aU2, zb, u2, tile, nullptr, nullptr);
    }
}

// ---------- analytic stage-1 stats ----------
__global__ void k_stats1a(const float* __restrict__ u, const float* __restrict__ v,
                          const float* __restrict__ u2, const int* __restrict__ od,
                          const int* __restrict__ id, double* __restrict__ stats_raw) {
    __shared__ double lsum[4][64], lsq[4][64];
    int tid = threadIdx.x, c = tid & 63, w = tid >> 6;
    double a1 = 0.0, a2 = 0.0;
    for (int n = blockIdx.x * 4 + w; n < NN; n += gridDim.x * 4) {
        double uu = u[(size_t)n * 64 + c], vv = v[(size_t)n * 64 + c];
        double uu2 = u2[(size_t)n * 64 + c];
        double wod = 1.0 + od[n], wid = 1.0 + id[n];
        a1 += wod * uu + wid * vv;
        a2 += wod * uu * uu + wid * vv * vv + 2.0 * vv * uu2;
    }
    lsum[w][c] = a1; lsq[w][c] = a2;
    __syncthreads();
    if (w == 0) {
        a1 = lsum[0][c] + lsum[1][c] + lsum[2][c] + lsum[3][c];
        a2 = lsq[0][c] + lsq[1][c] + lsq[2][c] + lsq[3][c];
        atomAddD(&stats_raw[c], a1);
        atomAddD(&stats_raw[64 + c], a2);
    }
}

__global__ void k_fin1(const double* __restrict__ raw, const float* __restrict__ b,
                       float* __restrict__ fin, double inv_cnt) {
    int c = threadIdx.x;
    double m1 = raw[c] * inv_cnt;
    double var = raw[64 + c] * inv_cnt - m1 * m1;
    if (var < 0.0) var = 0.0;
    fin[c] = (float)(m1 + (double)b[c]);
    fin[64 + c] = (float)(1.0 / sqrt(var + 1e-5));
}

__global__ void k_fin(const double* __restrict__ raw, float* __restrict__ fin, double inv_cnt) {
    int c = threadIdx.x;
    double mean = raw[c] * inv_cnt;
    double var = raw[64 + c] * inv_cnt - mean * mean;
    if (var < 0.0) var = 0.0;
    fin[c] = (float)mean;
    fin[64 + c] = (float)(1.0 / sqrt(var + 1e-5));
}

// ---------- s_tab[n] = relu(bn1(u[n]+v[n]+b)) + sum_{e:dst=n} relu(bn1(u[src]+v[n]+b)) ----------
__global__ void k_s1_csr(const float* __restrict__ u, const float* __restrict__ v,
                         const int* __restrict__ off, const int* __restrict__ srcs,
                         const float* __restrict__ b_un, const float* __restrict__ fin,
                         const float* __restrict__ g1, const float* __restrict__ be1,
                         float* __restrict__ s_tab) {
    int team = (blockIdx.x * 256 + threadIdx.x) >> 6;
    int c = threadIdx.x & 63;
    float sc = fin[64 + c] * g1[c];
    float tsh = (b_un[c] - fin[c]) * sc + be1[c];
    float vn = v[(size_t)team * 64 + c];
    float a[8] = {fmaxf((u[(size_t)team * 64 + c] + vn) * sc + tsh, 0.f),
                  0.f, 0.f, 0.f, 0.f, 0.f, 0.f, 0.f};
    int e = off[team], e1 = off[team + 1];
    for (; e + 7 < e1; e += 8)
#pragma unroll
        for (int j = 0; j < 8; j++)
            a[j] += fmaxf((u[(size_t)srcs[e + j] * 64 + c] + vn) * sc + tsh, 0.f);
    for (; e < e1; e++) a[0] += fmaxf((u[(size_t)srcs[e] * 64 + c] + vn) * sc + tsh, 0.f);
    s_tab[(size_t)team * 64 + c] = ((a[0] + a[1]) + (a[2] + a[3])) + ((a[4] + a[5]) + (a[6] + a[7]));
}

// ---------- msg[n] = sum_{e:dst=n} s_tab[src_e] ----------
__global__ void k_msg_csr(const int* __restrict__ off, const int* __restrict__ srcs,
                          const float* __restrict__ s_tab, float* __restrict__ msg) {
    int team = (blockIdx.x * 256 + threadIdx.x) >> 6;
    int c = threadIdx.x & 63;
    float a[8] = {0.f, 0.f, 0.f, 0.f, 0.f, 0.f, 0.f, 0.f};
    int e = off[team], e1 = off[team + 1];
    for (; e + 7 < e1; e += 8)
#pragma unroll
        for (int j = 0; j < 8; j++) a[j] += s_tab[(size_t)srcs[e + j] * 64 + c];
    for (; e < e1; e++) a[0] += s_tab[(size_t)srcs[e] * 64 + c];
    msg[(size_t)team * 64 + c] = ((a[0] + a[1]) + (a[2] + a[3])) + ((a[4] + a[5]) + (a[6] + a[7]));
}

// ---------- mb = msg @ W_gc[64:128]  (streaming, IN PLACE over msg) ----------
__global__ void k_mb(float* msg, const float* __restrict__ W) {
    __shared__ float lds[4][16 * 68];
    const int lane = threadIdx.x & 63;
    const int wid = threadIdx.x >> 6;
    const int m = lane & 15, quad = lane >> 4;
    const int gwave = (blockIdx.x * blockDim.x + threadIdx.x) >> 6;
    const int nwaves = (gridDim.x * blockDim.x) >> 6;
    float* wl = lds[wid];

    bf16x8 wfh[2][4], wfl[2][4];
#pragma unroll
    for (int kk = 0; kk < 2; kk++)
#pragma unroll
        for (int ct = 0; ct < 4; ct++) {
            float wv[8];
#pragma unroll
            for (int j = 0; j < 8; j++)
                wv[j] = W[(kk * 32 + quad * 8 + j) * 64 + ct * 16 + m];
            split8r(wv, wfh[kk][ct], wfl[kk][ct]);
        }
    float zb[4] = {0.f, 0.f, 0.f, 0.f};

    for (int tile = gwave; tile < NT_N; tile += nwaves) {
        const int r = (tile << 4) + m;
        bf16x8 ah[2], al[2];
        split8(msg + (size_t)r * 64 + quad * 8,      ah[0], al[0]);
        split8(msg + (size_t)r * 64 + 32 + quad * 8, ah[1], al[1]);

        f32x4 zero = {0.f, 0.f, 0.f, 0.f};
        f32x4 acc[4];
#pragma unroll
        for (int ct = 0; ct < 4; ct++) {
            acc[ct] = zero;
#pragma unroll
            for (int kk = 0; kk < 2; kk++) {
                acc[ct] = __builtin_amdgcn_mfma_f32_16x16x32_bf16(al[kk], wfh[kk][ct], acc[ct], 0, 0, 0);
                acc[ct] = __builtin_amdgcn_mfma_f32_16x16x32_bf16(ah[kk], wfl[kk][ct], acc[ct], 0, 0, 0);
                acc[ct] = __builtin_amdgcn_mfma_f32_16x16x32_bf16(ah[kk], wfh[kk][ct], acc[ct], 0, 0, 0);
            }
        }
        epi_tile<false, false>(wl, lane, acc, zb, msg, tile, nullptr, nullptr);
    }
}

// ---------- stage-2: h2_pre[row] = relu(bn1(u[sr]+v[dm]+b_un)) @ Wtop2 + mb[dm] + b_gc
// K=64; dst-sorted edge rows. h2pre written with NON-TEMPORAL stores so the 218 MB
// stream does not evict the L3-resident u/v/mb gather tables (R10: that eviction made
// the u-gather re-fetch 400 MB from HBM).
__global__ void k_ph0(const float* __restrict__ u, const float* __restrict__ v,
                      const float* __restrict__ mb, const int* __restrict__ srcs_s,
                      const int* __restrict__ dsts_s,
                      const float* __restrict__ W, const float* __restrict__ b_un,
                      const float* __restrict__ b_gc,
                      const float* __restrict__ fin1, const float* __restrict__ g1,
                      const float* __restrict__ be1,
                      float* __restrict__ h2pre, double* __restrict__ stats_raw) {
    __shared__ float lds[4][16 * 68];
    const int lane = threadIdx.x & 63;
    const int wid = threadIdx.x >> 6;
    const int m = lane & 15, quad = lane >> 4;
    const int gwave = (blockIdx.x * blockDim.x + threadIdx.x) >> 6;
    const int nwaves = (gridDim.x * blockDim.x) >> 6;
    float* wl = lds[wid];

    bf16x8 wfh[2][4], wfl[2][4];
#pragma unroll
    for (int kk = 0; kk < 2; kk++)
#pragma unroll
        for (int ct = 0; ct < 4; ct++) {
            float wv[8];
#pragma unroll
            for (int j = 0; j < 8; j++)
                wv[j] = W[(kk * 32 + quad * 8 + j) * 64 + ct * 16 + m];
            split8r(wv, wfh[kk][ct], wfl[kk][ct]);
        }

    float bv[4];
#pragma unroll
    for (int ct = 0; ct < 4; ct++) bv[ct] = b_gc[ct * 16 + m];

    float s1f[2][8], t1f[2][8];
#pragma unroll
    for (int kk = 0; kk < 2; kk++)
#pragma unroll
        for (int j = 0; j < 8; j++) {
            int c = kk * 32 + quad * 8 + j;
            float sc = fin1[64 + c] * g1[c];
            s1f[kk][j] = sc;
            t1f[kk][j] = be1[c] + (b_un[c] - fin1[c]) * sc;
        }

    double ssum[4] = {0,0,0,0}, ssq[4] = {0,0,0,0};

    for (int tile = gwave; tile < NT_R; tile += nwaves) {
        const int r = (tile << 4) + m;
        const bool selftile = (tile < NT_N);
        int sr = selftile ? r : srcs_s[r - NN];
        int dm = selftile ? r : dsts_s[r - NN];

        bf16x8 ah[2], al[2];
#pragma unroll
        for (int kk = 0; kk < 2; kk++) {
            f32x4 u0 = *reinterpret_cast<const f32x4*>(u + (size_t)sr * 64 + kk * 32 + quad * 8);
            f32x4 u1 = *reinterpret_cast<const f32x4*>(u + (size_t)sr * 64 + kk * 32 + quad * 8 + 4);
            f32x4 v0 = *reinterpret_cast<const f32x4*>(v + (size_t)dm * 64 + kk * 32 + quad * 8);
            f32x4 v1 = *reinterpret_cast<const f32x4*>(v + (size_t)dm * 64 + kk * 32 + quad * 8 + 4);
            float tv[8];
#pragma unroll
            for (int j = 0; j < 4; j++) {
                tv[j]     = fmaxf((u0[j] + v0[j]) * s1f[kk][j]     + t1f[kk][j],     0.f);
                tv[4 + j] = fmaxf((u1[j] + v1[j]) * s1f[kk][4 + j] + t1f[kk][4 + j], 0.f);
            }
            split8r(tv, ah[kk], al[kk]);
        }

        f32x4 zero = {0.f, 0.f, 0.f, 0.f};
        f32x4 acc[4];
#pragma unroll
        for (int ct = 0; ct < 4; ct++) {
            acc[ct] = zero;
#pragma unroll
            for (int kk = 0; kk < 2; kk++) {
                acc[ct] = __builtin_amdgcn_mfma_f32_16x16x32_bf16(al[kk], wfh[kk][ct], acc[ct], 0, 0, 0);
                acc[ct] = __builtin_amdgcn_mfma_f32_16x16x32_bf16(ah[kk], wfl[kk][ct], acc[ct], 0, 0, 0);
                acc[ct] = __builtin_amdgcn_mfma_f32_16x16x32_bf16(ah[kk], wfh[kk][ct], acc[ct], 0, 0, 0);
            }
        }

        // add mb[dm_of_row] + b_gc per element, then stats + LDS-coalesced NT store
#pragma unroll
        for (int i = 0; i < 4; i++) {
            int dmv = __shfl(dm, (lane & 48) + quad * 4 + i, 64);   // dm of row quad*4+i
#pragma unroll
            for (int ct = 0; ct < 4; ct++) {
                float val = acc[ct][i] + bv[ct] + mb[(size_t)dmv * 64 + ct * 16 + m];
                wl[(quad * 4 + i) * 68 + ct * 16 + m] = val;
                ssum[ct] += (double)val;
                ssq[ct]  += (double)val * (double)val;
            }
        }
        asm volatile("s_waitcnt lgkmcnt(0)" ::: "memory");
#pragma unroll
        for (int j = 0; j < 4; j++) {
            int row = j * 4 + quad;
            f32x4 vv = *reinterpret_cast<const f32x4*>(wl + row * 68 + m * 4);
            __builtin_nontemporal_store(vv,
                reinterpret_cast<f32x4*>(h2pre + ((size_t)(tile << 4) + row) * 64 + m * 4));
        }
    }

#pragma unroll
    for (int ct = 0; ct < 4; ct++) {
        double sv = ssum[ct], qv = ssq[ct];
        sv += __shfl_xor(sv, 16, 64); sv += __shfl_xor(sv, 32, 64);
        qv += __shfl_xor(qv, 16, 64); qv += __shfl_xor(qv, 32, 64);
        if (quad == 0) {
            atomAddD(&stats_raw[ct * 16 + m], sv);
            atomAddD(&stats_raw[64 + ct * 16 + m], qv);
        }
    }
}

// ---------- agg[n] = relu(bn2(h2pre[n])) + sum_{q in src-CSR} relu(bn2(h2pre[NN+perm_s[q]]))
// No atomics; h2pre rows are single-use -> NON-TEMPORAL loads (don't pollute caches).
__global__ void k_agg_csr(const float* __restrict__ h2pre, const int* __restrict__ off_s,
                          const int* __restrict__ perm_s, const float* __restrict__ fin2,
                          const float* __restrict__ g2, const float* __restrict__ be2,
                          float* __restrict__ agg) {
    int n = (blockIdx.x * 256 + threadIdx.x) >> 6;
    int c = threadIdx.x & 63;
    float sc = fin2[64 + c] * g2[c];
    float sh = be2[c] - fin2[c] * sc;
    float a[8] = {fmaxf(h2pre[(size_t)n * 64 + c] * sc + sh, 0.f),
                  0.f, 0.f, 0.f, 0.f, 0.f, 0.f, 0.f};
    int q = off_s[n], q1 = off_s[n + 1];
    for (; q + 7 < q1; q += 8)
#pragma unroll
        for (int j = 0; j < 8; j++) {
            float hv = __builtin_nontemporal_load(
                h2pre + (size_t)(NN + perm_s[q + j]) * 64 + c);
            a[j] += fmaxf(hv * sc + sh, 0.f);
        }
    for (; q < q1; q++) {
        float hv = __builtin_nontemporal_load(h2pre + (size_t)(NN + perm_s[q]) * 64 + c);
        a[0] += fmaxf(hv * sc + sh, 0.f);
    }
    agg[(size_t)n * 64 + c] = ((a[0] + a[1]) + (a[2] + a[3])) + ((a[4] + a[5]) + (a[6] + a[7]));
}

// ---------- stage 3: t_pre = [relu(bn2(h2pre[:N])), agg] @ W_tr + b_tr, stats3 ----------
__global__ void k_mm3(const float* __restrict__ h2pre, const float* __restrict__ agg,
                      const float* __restrict__ W, const float* __restrict__ bias,
                      const float* __restrict__ fin2, const float* __restrict__ g2,
                      const float* __restrict__ be2,
                      float* __restrict__ outp, double* __restrict__ stats_raw) {
    __shared__ float lds[4][16 * 68];
    const int lane = threadIdx.x & 63;
    const int wid = threadIdx.x >> 6;
    const int m = lane & 15, quad = lane >> 4;
    const int gwave = (blockIdx.x * blockDim.x + threadIdx.x) >> 6;
    const int nwaves = (gridDim.x * blockDim.x) >> 6;
    float* wl = lds[wid];

    bf16x8 wfh[4][4], wfl[4][4];
#pragma unroll
    for (int kk = 0; kk < 4; kk++)
#pragma unroll
        for (int ct = 0; ct < 4; ct++) {
            float wv[8];
#pragma unroll
            for (int j = 0; j < 8; j++)
                wv[j] = W[(kk * 32 + quad * 8 + j) * 64 + ct * 16 + m];
            split8r(wv, wfh[kk][ct], wfl[kk][ct]);
        }

    float bv[4];
#pragma unroll
    for (int ct = 0; ct < 4; ct++) bv[ct] = bias[ct * 16 + m];

    float s2f[2][8], t2f[2][8];
#pragma unroll
    for (int kk = 0; kk < 2; kk++)
#pragma unroll
        for (int j = 0; j < 8; j++) {
            int c = kk * 32 + quad * 8 + j;
            float sc = fin2[64 + c] * g2[c];
            s2f[kk][j] = sc;
            t2f[kk][j] = be2[c] - fin2[c] * sc;
        }

    double ssum[4] = {0,0,0,0}, ssq[4] = {0,0,0,0};

    for (int tile = gwave; tile < NT_N; tile += nwaves) {
        const int r = (tile << 4) + m;
        bf16x8 ah[4], al[4];
#pragma unroll
        for (int kk = 0; kk < 2; kk++) {
            f32x4 v0 = __builtin_nontemporal_load(
                reinterpret_cast<const f32x4*>(h2pre + (size_t)r * 64 + kk * 32 + quad * 8));
            f32x4 v1 = __builtin_nontemporal_load(
                reinterpret_cast<const f32x4*>(h2pre + (size_t)r * 64 + kk * 32 + quad * 8 + 4));
            float tv[8];
#pragma unroll
            for (int j = 0; j < 4; j++) {
                tv[j]     = fmaxf(v0[j] * s2f[kk][j]     + t2f[kk][j],     0.f);
                tv[4 + j] = fmaxf(v1[j] * s2f[kk][4 + j] + t2f[kk][4 + j], 0.f);
            }
            split8r(tv, ah[kk], al[kk]);
        }
        split8(agg + (size_t)r * 64 + quad * 8,      ah[2], al[2]);
        split8(agg + (size_t)r * 64 + 32 + quad * 8, ah[3], al[3]);

        f32x4 zero = {0.f, 0.f, 0.f, 0.f};
        f32x4 acc[4];
#pragma unroll
        for (int ct = 0; ct < 4; ct++) {
            acc[ct] = zero;
#pragma unroll
            for (int kk = 0; kk < 4; kk++)
                acc[ct] = __builtin_amdgcn_mfma_f32_16x16x32_bf16(al[kk], wfh[kk][ct], acc[ct], 0, 0, 0);
#pragma unroll
            for (int kk = 0; kk < 4; kk++)
                acc[ct] = __builtin_amdgcn_mfma_f32_16x16x32_bf16(ah[kk], wfl[kk][ct], acc[ct], 0, 0, 0);
#pragma unroll
            for (int kk = 0; kk < 4; kk++)
                acc[ct] = __builtin_amdgcn_mfma_f32_16x16x32_bf16(ah[kk], wfh[kk][ct], acc[ct], 0, 0, 0);
        }

        epi_tile<false, true>(wl, lane, acc, bv, outp, tile, ssum, ssq);
    }

#pragma unroll
    for (int ct = 0; ct < 4; ct++) {
        double sv = ssum[ct], qv = ssq[ct];
        sv += __shfl_xor(sv, 16, 64); sv += __shfl_xor(sv, 32, 64);
        qv += __shfl_xor(qv, 16, 64); qv += __shfl_xor(qv, 32, 64);
        if (quad == 0) {
            atomAddD(&stats_raw[ct * 16 + m], sv);
            atomAddD(&stats_raw[64 + ct * 16 + m], qv);
        }
    }
}

// ---------- stage 4 ----------
__global__ void k_mm4(const float* __restrict__ tpre, const float* __restrict__ W,
                      const float* __restrict__ bias, const float* __restrict__ fin3,
                      const float* __restrict__ g2, const float* __restrict__ be2,
                      float* __restrict__ outp, double* __restrict__ stats_raw) {
    __shared__ float lds[4][16 * 68];
    const int lane = threadIdx.x & 63;
    const int wid = threadIdx.x >> 6;
    const int m = lane & 15, quad = lane >> 4;
    const int gwave = (blockIdx.x * blockDim.x + threadIdx.x) >> 6;
    const int nwaves = (gridDim.x * blockDim.x) >> 6;
    float* wl = lds[wid];

    bf16x8 wfh[2][4], wfl[2][4];
#pragma unroll
    for (int kk = 0; kk < 2; kk++)
#pragma unroll
        for (int ct = 0; ct < 4; ct++) {
            float wv[8];
#pragma unroll
            for (int j = 0; j < 8; j++)
                wv[j] = W[(kk * 32 + quad * 8 + j) * 64 + ct * 16 + m];
            split8r(wv, wfh[kk][ct], wfl[kk][ct]);
        }

    float bv[4];
#pragma unroll
    for (int ct = 0; ct < 4; ct++) bv[ct] = bias[ct * 16 + m];

    float sc[2][8], sh[2][8];
#pragma unroll
    for (int kk = 0; kk < 2; kk++)
#pragma unroll
        for (int j = 0; j < 8; j++) {
            int c = kk * 32 + quad * 8 + j;
            float s = fin3[64 + c] * g2[c];
            sc[kk][j] = s;
            sh[kk][j] = be2[c] - fin3[c] * s;
        }

    double ssum[4] = {0,0,0,0}, ssq[4] = {0,0,0,0};

    for (int tile = gwave; tile < NT_N; tile += nwaves) {
        const int r = (tile << 4) + m;
        bf16x8 ah[2], al[2];
#pragma unroll
        for (int kk = 0; kk < 2; kk++) {
            f32x4 v0 = *reinterpret_cast<const f32x4*>(tpre + (size_t)r * 64 + kk * 32 + quad * 8);
            f32x4 v1 = *reinterpret_cast<const f32x4*>(tpre + (size_t)r * 64 + kk * 32 + quad * 8 + 4);
            float tv[8];
#pragma unroll
            for (int j = 0; j < 4; j++) {
                tv[j]     = fmaxf(v0[j] * sc[kk][j]     + sh[kk][j],     0.f);
                tv[4 + j] = fmaxf(v1[j] * sc[kk][4 + j] + sh[kk][4 + j], 0.f);
            }
            split8r(tv, ah[kk], al[kk]);
        }

        f32x4 zero = {0.f, 0.f, 0.f, 0.f};
        f32x4 acc[4];
#pragma unroll
        for (int ct = 0; ct < 4; ct++) {
            acc[ct] = zero;
#pragma unroll
            for (int kk = 0; kk < 2; kk++) {
                acc[ct] = __builtin_amdgcn_mfma_f32_16x16x32_bf16(al[kk], wfh[kk][ct], acc[ct], 0, 0, 0);
                acc[ct] = __builtin_amdgcn_mfma_f32_16x16x32_bf16(ah[kk], wfl[kk][ct], acc[ct], 0, 0, 0);
                acc[ct] = __builtin_amdgcn_mfma_f32_16x16x32_bf16(ah[kk], wfh[kk][ct], acc[ct], 0, 0, 0);
            }
        }

        epi_tile<true, true>(wl, lane, acc, bv, outp, tile, ssum, ssq);
    }

#pragma unroll
    for (int ct = 0; ct < 4; ct++) {
        double sv = ssum[ct], qv = ssq[ct];
        sv += __shfl_xor(sv, 16, 64); sv += __shfl_xor(sv, 32, 64);
        qv += __shfl_xor(qv, 16, 64); qv += __shfl_xor(qv, 32, 64);
        if (quad == 0) {
            atomAddD(&stats_raw[ct * 16 + m], sv);
            atomAddD(&stats_raw[64 + ct * 16 + m], qv);
        }
    }
}

// out = relu(bn(out_pre; stats4, g3, be3)) -> f32
__global__ void k_out(const float* __restrict__ op, const float* __restrict__ fin,
                      const float* __restrict__ g, const float* __restrict__ be,
                      float* __restrict__ out) {
    int i = blockIdx.x * 256 + threadIdx.x;   // covers NN*64 exactly
    int c = i & 63;
    out[i] = fmaxf((op[i] - fin[c]) * fin[64 + c] * g[c] + be[c], 0.f);
}

extern "C" void kernel_launch(void* const* d_in, const int* in_sizes, int n_in,
                              void* d_out, int out_size, void* d_ws, size_t ws_size,
                              hipStream_t stream) {
    const float* x    = (const float*)d_in[0];
    const int*   ei   = (const int*)d_in[1];
    const float* W_un = (const float*)d_in[2];
    const float* b_un = (const float*)d_in[3];
    const float* g1   = (const float*)d_in[4];
    const float* be1  = (const float*)d_in[5];
    const float* W_gc = (const float*)d_in[6];
    const float* b_gc = (const float*)d_in[7];
    const float* g2   = (const float*)d_in[8];
    const float* be2  = (const float*)d_in[9];
    const float* W_tr = (const float*)d_in[10];
    const float* b_tr = (const float*)d_in[11];
    const float* W_li = (const float*)d_in[12];
    const float* b_li = (const float*)d_in[13];
    const float* g3   = (const float*)d_in[14];
    const float* be3  = (const float*)d_in[15];

    float* ws = (float*)d_ws;
    const size_t FN = (size_t)NN * 64;           // 3.2M floats (12.8 MB)
    const size_t FR = (size_t)RR * 64;           // 54.4M floats (217.6 MB)
    float*  P0 = ws;
    float*  P1 = ws + FN;
    float*  P2 = ws + 2 * FN;
    float*  H  = ws + 3 * FN;
    float*  u      = P0;
    float*  v      = P1;
    float*  msg    = P2;          // becomes mb after k_mb (in place)
    float*  s_tab  = H;
    float*  dsum   = H + FN;
    float*  u2     = H + 2 * FN;
    float*  h2pre  = H;
    float*  agg    = P0;
    float*  tpre   = P1;
    float*  outpre = P2;
    double* stats_raw = (double*)(H + FR);
    int*    od        = (int*)(stats_raw + 512);
    int*    id        = od + NN;
    int*    off       = id + NN;
    int*    cursor    = off + NN + 1;
    int*    off_s     = cursor + NN;
    int*    cursor_s  = off_s + NN + 1;
    int*    srcs_s    = cursor_s + NN;
    int*    dsts_s    = srcs_s + EE;
    int*    perm_s    = dsts_s + EE;
    float*  stats_fin = (float*)(perm_s + EE);

    // zero: stats_raw + od + id (contiguous)
    hipMemsetAsync(stats_raw, 0, 512 * sizeof(double) + 2 * NN * sizeof(int), stream);

    // build dst-sorted edge list + src-CSR permutation
    k_deg  <<<3125, 256,  0, stream>>>(ei, od, id);
    k_scan <<<1,    1024, 0, stream>>>(id, off, cursor);      // dst-CSR
    k_scan <<<1,    1024, 0, stream>>>(od, off_s, cursor_s);  // src-CSR
    k_fill <<<3125, 256,  0, stream>>>(ei, cursor, srcs_s, dsts_s);
    k_fill2<<<3125, 256,  0, stream>>>(srcs_s, cursor_s, perm_s);

    // stage 0 + per-node tables
    k_dsum_csr<<<12500, 256, 0, stream>>>(x, off, srcs_s, dsum);
    k_uv3<<<512, 256, 0, stream>>>(x, dsum, W_un, u, v, u2);

    // stage-1: analytic stats, then CSR reductions
    k_stats1a<<<256, 256, 0, stream>>>(u, v, u2, od, id, stats_raw + 0);
    k_fin1<<<1, 64, 0, stream>>>(stats_raw + 0, b_un, stats_fin + 0, 1.0 / (double)RR);
    k_s1_csr<<<12500, 256, 0, stream>>>(u, v, off, srcs_s, b_un, stats_fin + 0, g1, be1, s_tab);
    k_msg_csr<<<12500, 256, 0, stream>>>(off, srcs_s, s_tab, msg);
    k_mb<<<512, 256, 0, stream>>>(msg, W_gc + 64 * 64);       // msg -> mb in place

    // stage-2: one gather pass (K=64, NT-stored h2pre + stats), then src-CSR aggregate
    k_ph0<<<2048, 256, 0, stream>>>(u, v, msg, srcs_s, dsts_s, W_gc, b_un, b_gc,
                                    stats_fin + 0, g1, be1, h2pre, stats_raw + 128);
    k_fin<<<1, 64, 0, stream>>>(stats_raw + 128, stats_fin + 128, 1.0 / (double)RR);
    k_agg_csr<<<12500, 256, 0, stream>>>(h2pre, off_s, perm_s, stats_fin + 128, g2, be2, agg);

    // stage 3
    k_mm3<<<512, 256, 0, stream>>>(h2pre, agg, W_tr, b_tr, stats_fin + 128, g2, be2,
                                   tpre, stats_raw + 256);
    k_fin<<<1, 64, 0, stream>>>(stats_raw + 256, stats_fin + 256, 1.0 / (double)NN);

    // stage 4
    k_mm4<<<512, 256, 0, stream>>>(tpre, W_li, b_li, stats_fin + 256, g2, be2,
                                   outpre, stats_raw + 384);
    k_fin<<<1, 64, 0, stream>>>(stats_raw + 384, stats_fin + 384, 1.0 / (double)NN);

    k_out<<<12500, 256, 0, stream>>>(outpre, stats_fin + 384, g3, be3, (float*)d_out);
}